// Round 1
// baseline (1333.274 us; speedup 1.0000x reference)
//
#include <hip/hip_runtime.h>
#include <cfloat>
#include <cmath>

// Problem constants (fixed by reference)
static constexpr int NN   = 10000;   // nodes
static constexpr int NE   = 160000;  // edges
static constexpr int NA   = 8;       // arg nodes / masks
static constexpr int D1   = 512;     // HID*HEADS
static constexpr int EMBD = 128;
static constexpr int NATTR= 64;
static constexpr int OUTD = 64;
static constexpr int NFR  = 1500;
static constexpr int NRO  = 64;
static constexpr int AGG_NB = 64;    // partial-reduction blocks for softmax aggr

// ---------------- gather p_emb = pred_emb[node_pred] ----------------
__global__ void k_gather_pemb(const int* __restrict__ node_pred,
                              const float* __restrict__ pred_emb,
                              float* __restrict__ pemb) {
    int idx = blockIdx.x * blockDim.x + threadIdx.x;       // over NN*32 float4
    int total = NN * (EMBD / 4);
    if (idx >= total) return;
    int n = idx >> 5, j = idx & 31;
    const float4* s = (const float4*)(pred_emb + (size_t)node_pred[n] * EMBD);
    ((float4*)(pemb + (size_t)n * EMBD))[j] = s[j];
}

// ---------------- attr tables: attr_ee{1,2}[a] = pred_emb[a] @ We{1,2} ----------------
__global__ void k_attr_ee(const float* __restrict__ pred_emb,
                          const float* __restrict__ We1, const float* __restrict__ We2,
                          float* __restrict__ t1, float* __restrict__ t2) {
    int a = blockIdx.x & 63;
    int which = blockIdx.x >> 6;
    const float* We = which ? We2 : We1;
    float* out = which ? t2 : t1;
    __shared__ float row[EMBD];
    if (threadIdx.x < EMBD) row[threadIdx.x] = pred_emb[a * EMBD + threadIdx.x];
    __syncthreads();
    int c = threadIdx.x;   // 512 threads
    float acc = 0.f;
    for (int k = 0; k < EMBD; ++k) acc += row[k] * We[k * D1 + c];
    out[a * D1 + c] = acc;
}

// ---------------- CSR build ----------------
__global__ void k_indeg(const int* __restrict__ dst, int* __restrict__ counts) {
    int stride = gridDim.x * blockDim.x;
    for (int e = blockIdx.x * blockDim.x + threadIdx.x; e < NE; e += stride)
        atomicAdd(&counts[dst[e]], 1);
}

__global__ __launch_bounds__(1024) void k_scan(const int* __restrict__ counts,
                                               int* __restrict__ row_ptr,
                                               int* __restrict__ cursor) {
    __shared__ int s[1024];
    __shared__ int base_s;
    int t = threadIdx.x;
    if (t == 0) base_s = 0;
    __syncthreads();
    for (int c0 = 0; c0 < NN; c0 += 1024) {
        int v = (c0 + t < NN) ? counts[c0 + t] : 0;
        s[t] = v; __syncthreads();
        for (int off = 1; off < 1024; off <<= 1) {
            int add = (t >= off) ? s[t - off] : 0;
            __syncthreads();
            s[t] += add;
            __syncthreads();
        }
        int base = base_s;
        int excl = base + s[t] - v;
        if (c0 + t < NN) { row_ptr[c0 + t] = excl; cursor[c0 + t] = excl; }
        __syncthreads();
        if (t == 0) base_s = base + s[1023];
        __syncthreads();
    }
    if (t == 0) row_ptr[NN] = base_s;
}

__global__ void k_scatter(const int* __restrict__ src, const int* __restrict__ dst,
                          const int* __restrict__ attr, int* __restrict__ cursor,
                          int* __restrict__ csr_src, int* __restrict__ csr_attr) {
    int stride = gridDim.x * blockDim.x;
    for (int e = blockIdx.x * blockDim.x + threadIdx.x; e < NE; e += stride) {
        int pos = atomicAdd(&cursor[dst[e]], 1);
        csr_src[pos] = src[e];
        csr_attr[pos] = attr[e];
    }
}

// ---------------- k-hop masks (bit-parallel over 8 seeds, double-buffered) ----------------
__global__ void k_mask_seed(const int* __restrict__ arg_nodes, unsigned* __restrict__ mask) {
    if (threadIdx.x < NA) atomicOr(&mask[arg_nodes[threadIdx.x]], 1u << threadIdx.x);
}

__global__ void k_prop(const unsigned* __restrict__ oldm, unsigned* __restrict__ newm,
                       const int* __restrict__ src, const int* __restrict__ dst) {
    int stride = gridDim.x * blockDim.x;
    int t0 = blockIdx.x * blockDim.x + threadIdx.x;
    for (int n = t0; n < NN; n += stride) atomicOr(&newm[n], oldm[n]);   // newm pre-zeroed
    for (int e = t0; e < NE; e += stride) {
        unsigned v = oldm[dst[e]];
        if (v) atomicOr(&newm[src[e]], v);
    }
}

// ---------------- per-(full+8 masks) attr histogram of kept edges ----------------
__global__ void k_hist(const int* __restrict__ src, const int* __restrict__ dst,
                       const int* __restrict__ attr, const unsigned* __restrict__ mask,
                       unsigned* __restrict__ hist) {
    __shared__ unsigned lh[9 * 64];
    for (int i = threadIdx.x; i < 9 * 64; i += blockDim.x) lh[i] = 0;
    __syncthreads();
    int stride = gridDim.x * blockDim.x;
    for (int e = blockIdx.x * blockDim.x + threadIdx.x; e < NE; e += stride) {
        int a = attr[e] & 63;
        atomicAdd(&lh[a], 1u);
        unsigned bits = mask[src[e]] & mask[dst[e]];
        while (bits) {
            int i = __ffs(bits) - 1;
            bits &= bits - 1;
            atomicAdd(&lh[(1 + i) * 64 + a], 1u);
        }
    }
    __syncthreads();
    for (int i = threadIdx.x; i < 9 * 64; i += blockDim.x)
        if (lh[i]) atomicAdd(&hist[i], lh[i]);
}

// ---------------- mean_ee: (sum_a hist[a]*pred_emb[a] / max(tot,1)) @ We ----------------
__global__ __launch_bounds__(512) void k_mean_ee(const unsigned* __restrict__ hist,
                                                 const float* __restrict__ pred_emb,
                                                 const float* __restrict__ We1,
                                                 const float* __restrict__ We2,
                                                 float* __restrict__ mee1,
                                                 float* __restrict__ mee2) {
    int g = blockIdx.x;  // 0=full (layer1/We1), 1..8 = masks (layer2/We2)
    const float* We = (g == 0) ? We1 : We2;
    float* out = (g == 0) ? mee1 : (mee2 + (g - 1) * D1);
    __shared__ float cnt[64];
    __shared__ float me[EMBD];
    __shared__ float tot_s;
    if (threadIdx.x < 64) cnt[threadIdx.x] = (float)hist[g * 64 + threadIdx.x];
    __syncthreads();
    if (threadIdx.x == 0) {
        float tt = 0.f;
        for (int a = 0; a < 64; ++a) tt += cnt[a];
        tot_s = fmaxf(tt, 1.0f);
    }
    __syncthreads();
    if (threadIdx.x < EMBD) {
        float acc = 0.f;
        for (int a = 0; a < 64; ++a) acc += cnt[a] * pred_emb[a * EMBD + threadIdx.x];
        me[threadIdx.x] = acc / tot_s;
    }
    __syncthreads();
    int c = threadIdx.x;
    float acc = 0.f;
    for (int k = 0; k < EMBD; ++k) acc += me[k] * We[k * D1 + c];
    out[c] = acc;
}

// ---------------- fp32 GEMM  C[M,N] = A[M,K] @ B[K,N]  (128x128 tile, 8x8/thread) ----------------
__global__ __launch_bounds__(256) void k_gemm(const float* __restrict__ A,
                                              const float* __restrict__ B,
                                              float* __restrict__ C,
                                              int M, int K, int N) {
    __shared__ __align__(16) float As[16][132];  // [k][m], pad 4 -> 16B-aligned rows, low conflict
    __shared__ __align__(16) float Bs[16][128];
    int tid = threadIdx.x;
    int bm = blockIdx.y * 128;
    int bn = blockIdx.x * 128;
    int tm = (tid & 15) * 8;
    int tn = (tid >> 4) * 8;
    float acc[8][8] = {};
    for (int k0 = 0; k0 < K; k0 += 16) {
#pragma unroll
        for (int i = 0; i < 2; ++i) {
            int idx4 = tid + i * 256;           // 0..511 float4s
            int m  = idx4 >> 2;                 // 0..127
            int k4 = (idx4 & 3) * 4;            // 0,4,8,12
            float4 a = make_float4(0.f, 0.f, 0.f, 0.f);
            if (bm + m < M) a = *(const float4*)&A[(size_t)(bm + m) * K + k0 + k4];
            As[k4 + 0][m] = a.x; As[k4 + 1][m] = a.y; As[k4 + 2][m] = a.z; As[k4 + 3][m] = a.w;
            int kb = idx4 >> 5;                 // 0..15
            int n4 = (idx4 & 31) * 4;
            *(float4*)&Bs[kb][n4] = *(const float4*)&B[(size_t)(k0 + kb) * N + bn + n4];
        }
        __syncthreads();
#pragma unroll
        for (int k = 0; k < 16; ++k) {
            float a[8], b[8];
            *(float4*)&a[0] = *(const float4*)&As[k][tm];
            *(float4*)&a[4] = *(const float4*)&As[k][tm + 4];
            *(float4*)&b[0] = *(const float4*)&Bs[k][tn];
            *(float4*)&b[4] = *(const float4*)&Bs[k][tn + 4];
#pragma unroll
            for (int i = 0; i < 8; ++i)
#pragma unroll
                for (int j = 0; j < 8; ++j) acc[i][j] += a[i] * b[j];
        }
        __syncthreads();
    }
#pragma unroll
    for (int i = 0; i < 8; ++i) {
        int row = bm + tm + i;
        if (row < M) {
            *(float4*)&C[(size_t)row * N + bn + tn]     = make_float4(acc[i][0], acc[i][1], acc[i][2], acc[i][3]);
            *(float4*)&C[(size_t)row * N + bn + tn + 4] = make_float4(acc[i][4], acc[i][5], acc[i][6], acc[i][7]);
        }
    }
}

// ---------------- GATv2: one block per dst node, online softmax over in-edges + self-loop ----------------
__global__ __launch_bounds__(256) void k_gat(const float* __restrict__ xl,
                                             const float* __restrict__ xr,
                                             const float* __restrict__ attr_ee,
                                             const float* __restrict__ mean_ee,
                                             const float* __restrict__ att,
                                             const float* __restrict__ bias,
                                             const int* __restrict__ row_ptr,
                                             const int* __restrict__ csr_src,
                                             const int* __restrict__ csr_attr,
                                             const unsigned* __restrict__ mask, int bit,
                                             float* __restrict__ out) {
    int n = blockIdx.x;
    if (mask && !((mask[n] >> bit) & 1u)) return;  // unmasked dst: never read downstream
    int h = threadIdx.x >> 6;
    int l = threadIdx.x & 63;
    int c0 = h * 128 + l;
    int c1 = c0 + 64;
    float xr0 = xr[(size_t)n * D1 + c0];
    float xr1 = xr[(size_t)n * D1 + c1];
    float a0 = att[c0];   // att is [4][128] == [512]
    float a1 = att[c1];
    float m = -FLT_MAX, den = 0.f, acc0 = 0.f, acc1 = 0.f;
    int pend = row_ptr[n + 1];
    for (int p = row_ptr[n]; p <= pend; ++p) {     // p==pend is the self-loop
        int s;
        const float* ee;
        if (p == pend) { s = n; ee = mean_ee; }
        else {
            s = csr_src[p];
            if (mask && !((mask[s] >> bit) & 1u)) continue;  // masked edge: ex == 0 exactly
            ee = attr_ee + (csr_attr[p] & 63) * D1;
        }
        float xs0 = xl[(size_t)s * D1 + c0];
        float xs1 = xl[(size_t)s * D1 + c1];
        float z0 = xs0 + xr0 + ee[c0];
        float z1 = xs1 + xr1 + ee[c1];
        z0 = (z0 > 0.f) ? z0 : 0.2f * z0;
        z1 = (z1 > 0.f) ? z1 : 0.2f * z1;
        float ps = z0 * a0 + z1 * a1;
#pragma unroll
        for (int off = 32; off; off >>= 1) ps += __shfl_xor(ps, off, 64);
        float nm = fmaxf(m, ps);
        float sc = __expf(m - nm);
        float w  = __expf(ps - nm);
        den  = den * sc + w;
        acc0 = acc0 * sc + w * xs0;   // message is raw xl[src]
        acc1 = acc1 * sc + w * xs1;
        m = nm;
    }
    float inv = 1.f / (den + 1e-16f);
    out[(size_t)n * D1 + c0] = acc0 * inv + bias[c0];
    out[(size_t)n * D1 + c1] = acc1 * inv + bias[c1];
}

// ---------------- column softmax-aggregation (two-phase online) ----------------
__global__ __launch_bounds__(512) void k_aggr_partial(const float* __restrict__ x,
                                                      const unsigned* __restrict__ mask, int bit,
                                                      float* __restrict__ part) {
    int c = threadIdx.x;
    int rows = (NN + gridDim.x - 1) / gridDim.x;
    int r0 = blockIdx.x * rows;
    int r1 = min(NN, r0 + rows);
    float m = -FLT_MAX, den = 0.f, num = 0.f;
    for (int r = r0; r < r1; ++r) {
        if (mask && !((mask[r] >> bit) & 1u)) continue;
        float v = x[(size_t)r * D1 + c];
        float nm = fmaxf(m, v);
        float sc = __expf(m - nm);
        float w  = __expf(v - nm);
        den = den * sc + w;
        num = num * sc + w * v;
        m = nm;
    }
    part[(blockIdx.x * 3 + 0) * D1 + c] = m;
    part[(blockIdx.x * 3 + 1) * D1 + c] = den;
    part[(blockIdx.x * 3 + 2) * D1 + c] = num;
}

__global__ __launch_bounds__(512) void k_aggr_combine(const float* __restrict__ part, int nb,
                                                      float* __restrict__ out) {
    int c = threadIdx.x;
    float M = -FLT_MAX;
    for (int b = 0; b < nb; ++b) M = fmaxf(M, part[(b * 3) * D1 + c]);
    float den = 0.f, num = 0.f;
    for (int b = 0; b < nb; ++b) {
        float sc = __expf(part[(b * 3 + 0) * D1 + c] - M);
        den += part[(b * 3 + 1) * D1 + c] * sc;
        num += part[(b * 3 + 2) * D1 + c] * sc;
    }
    out[c] = num / den;
}

// ---------------- HGT stage A: kf/vf + kr/qr/vr (26 dots-of-512 blocks) ----------------
__global__ void k_hgt_a(const float* __restrict__ frame_x, const float* __restrict__ role_x,
                        const float* __restrict__ kqv_f, const float* __restrict__ kqvb_f,
                        const float* __restrict__ kqv_r, const float* __restrict__ kqvb_r,
                        float* __restrict__ kf, float* __restrict__ vf,
                        float* __restrict__ kr, float* __restrict__ qr, float* __restrict__ vr) {
    int b = blockIdx.x, j = threadIdx.x;   // 64 threads
    const float *x, *W, *bi;
    float* out;
    if (b == 0)      { x = frame_x;               W = kqv_f;                    bi = kqvb_f;            out = kf; }
    else if (b == 1) { x = frame_x;               W = kqv_f + 2 * D1 * OUTD;    bi = kqvb_f + 2 * OUTD; out = vf; }
    else if (b < 10) { int i = b - 2;  x = role_x + i * D1; W = kqv_r;                 bi = kqvb_r;            out = kr + i * OUTD; }
    else if (b < 18) { int i = b - 10; x = role_x + i * D1; W = kqv_r + D1 * OUTD;     bi = kqvb_r + OUTD;     out = qr + i * OUTD; }
    else             { int i = b - 18; x = role_x + i * D1; W = kqv_r + 2 * D1 * OUTD; bi = kqvb_r + 2 * OUTD; out = vr + i * OUTD; }
    float acc = bi[j];
    for (int k = 0; k < D1; ++k) acc += x[k] * W[k * OUTD + j];
    out[j] = acc;
}

// ---------------- HGT stage B: attention + aggregate + gelu + a-linears ----------------
__global__ __launch_bounds__(512) void k_hgt_b(const float* __restrict__ kf_g,
                                               const float* __restrict__ vf_g,
                                               const float* __restrict__ kr_g,
                                               const float* __restrict__ qr_g,
                                               const float* __restrict__ vr_g,
                                               const float* __restrict__ a_rel,
                                               const float* __restrict__ m_rel,
                                               const float* __restrict__ p_rel,
                                               const float* __restrict__ aW_f,
                                               const float* __restrict__ ab_f,
                                               const float* __restrict__ aW_r,
                                               const float* __restrict__ ab_r,
                                               float* __restrict__ out_f,
                                               float* __restrict__ out_r) {
    __shared__ float kf[64], vf[64], kr[512], qr[512], vr[512];
    __shared__ float ka1[64], vfm1[64], aggf[64], geluf[64];
    __shared__ float kra2[512], vrm[512], gelur[512];
    __shared__ float al[8][2];
    int t = threadIdx.x;
    if (t < 64) { kf[t] = kf_g[t]; vf[t] = vf_g[t]; }
    kr[t] = kr_g[t]; qr[t] = qr_g[t]; vr[t] = vr_g[t];
    __syncthreads();
    int i = t >> 6, j = t & 63;
    {
        float acc1 = 0.f, acc2 = 0.f;
        for (int k = 0; k < 64; ++k) {
            acc1 += kr[i * 64 + k] * a_rel[2 * 4096 + k * 64 + j];
            acc2 += vr[i * 64 + k] * m_rel[2 * 4096 + k * 64 + j];
        }
        kra2[t] = acc1; vrm[t] = acc2;
    }
    if (t < 64) {
        float acc1 = 0.f, acc2 = 0.f, acc3 = 0.f;
        for (int k = 0; k < 64; ++k) {
            acc1 += kf[k] * a_rel[1 * 4096 + k * 64 + j];
            acc2 += vf[k] * m_rel[0 * 4096 + k * 64 + j];
            acc3 += vf[k] * m_rel[1 * 4096 + k * 64 + j];
        }
        ka1[j] = acc1; aggf[j] = acc2; vfm1[j] = acc3;
    }
    __syncthreads();
    if (t < 8) {
        const float sq = 0.125f;
        float p1 = p_rel[1], p2 = p_rel[2];
        float sfr = 0.f, srr = 0.f;
        for (int d = 0; d < 64; ++d) {
            sfr += qr[t * 64 + d] * ka1[d];
            srr += qr[t * 64 + d] * kra2[t * 64 + d];
        }
        sfr *= sq * p1; srr *= sq * p2;
        float mx = fmaxf(sfr, srr);
        float e0 = __expf(sfr - mx), e1 = __expf(srr - mx);
        float inv = 1.f / (e0 + e1);
        al[t][0] = e0 * inv; al[t][1] = e1 * inv;
    }
    __syncthreads();
    {
        float av = al[i][0] * vfm1[j] + al[i][1] * vrm[t];
        gelur[t] = 0.5f * av * (1.f + erff(av * 0.70710678118654752f));
    }
    if (t < 64) geluf[t] = 0.5f * aggf[t] * (1.f + erff(aggf[t] * 0.70710678118654752f));
    __syncthreads();
    {
        float acc = ab_r[j];
        for (int k = 0; k < 64; ++k) acc += gelur[i * 64 + k] * aW_r[k * 64 + j];
        out_r[t] = acc;
    }
    if (t < 64) {
        float acc = ab_f[j];
        for (int k = 0; k < 64; ++k) acc += geluf[k] * aW_f[k * 64 + j];
        out_f[j] = acc;
    }
}

// ---------------- frame logits + log_softmax ----------------
__global__ void k_frame_logits(const float* __restrict__ out_f, const float* __restrict__ Wfr,
                               const float* __restrict__ bfr, float* __restrict__ flog) {
    __shared__ float xf[64];
    if (threadIdx.x < 64) xf[threadIdx.x] = out_f[threadIdx.x];
    __syncthreads();
    int j = blockIdx.x * blockDim.x + threadIdx.x;
    if (j >= NFR) return;
    float acc = bfr[j];
    for (int k = 0; k < 64; ++k) acc += xf[k] * Wfr[k * NFR + j];
    flog[j] = acc;
}

__global__ __launch_bounds__(512) void k_frame_lsm(const float* __restrict__ flog,
                                                   float* __restrict__ outp) {
    __shared__ float red[512];
    int t = threadIdx.x;
    float m = -FLT_MAX;
    for (int j = t; j < NFR; j += 512) m = fmaxf(m, flog[j]);
    red[t] = m; __syncthreads();
    for (int off = 256; off; off >>= 1) { if (t < off) red[t] = fmaxf(red[t], red[t + off]); __syncthreads(); }
    float M = red[0]; __syncthreads();
    float s = 0.f;
    for (int j = t; j < NFR; j += 512) s += __expf(flog[j] - M);
    red[t] = s; __syncthreads();
    for (int off = 256; off; off >>= 1) { if (t < off) red[t] += red[t + off]; __syncthreads(); }
    float lse = M + logf(red[0]);
    for (int j = t; j < NFR; j += 512) outp[j] = flog[j] - lse;
}

// ---------------- roles: out_r @ Wro + bro, per-row log_softmax (wave == row) ----------------
__global__ __launch_bounds__(512) void k_roles(const float* __restrict__ out_r,
                                               const float* __restrict__ Wro,
                                               const float* __restrict__ bro,
                                               float* __restrict__ outp) {
    int t = threadIdx.x;
    int i = t >> 6, j = t & 63;
    __shared__ float xr_s[512];
    xr_s[t] = out_r[t];
    __syncthreads();
    float acc = bro[j];
    for (int k = 0; k < 64; ++k) acc += xr_s[i * 64 + k] * Wro[k * 64 + j];
    float m = acc;
#pragma unroll
    for (int off = 32; off; off >>= 1) m = fmaxf(m, __shfl_xor(m, off, 64));
    float e = __expf(acc - m);
    float s = e;
#pragma unroll
    for (int off = 32; off; off >>= 1) s += __shfl_xor(s, off, 64);
    outp[NFR + t] = acc - m - logf(s);
}

// =====================================================================
extern "C" void kernel_launch(void* const* d_in, const int* in_sizes, int n_in,
                              void* d_out, int out_size, void* d_ws, size_t ws_size,
                              hipStream_t stream) {
    const int* node_pred  = (const int*)d_in[0];
    const int* edge_index = (const int*)d_in[1];
    const int* e_src = edge_index;
    const int* e_dst = edge_index + NE;
    const int* edge_attr  = (const int*)d_in[2];
    const int* arg_nodes  = (const int*)d_in[3];
    const float* pred_emb = (const float*)d_in[4];
    const float* Wl1 = (const float*)d_in[5];
    const float* Wr1 = (const float*)d_in[6];
    const float* We1 = (const float*)d_in[7];
    const float* att1 = (const float*)d_in[8];
    const float* b1  = (const float*)d_in[9];
    const float* Wl2 = (const float*)d_in[10];
    const float* Wr2 = (const float*)d_in[11];
    const float* We2 = (const float*)d_in[12];
    const float* att2 = (const float*)d_in[13];
    const float* b2  = (const float*)d_in[14];
    const float* kqv_f  = (const float*)d_in[15];
    const float* kqvb_f = (const float*)d_in[16];
    const float* kqv_r  = (const float*)d_in[17];
    const float* kqvb_r = (const float*)d_in[18];
    const float* a_rel  = (const float*)d_in[19];
    const float* m_rel  = (const float*)d_in[20];
    const float* p_rel  = (const float*)d_in[21];
    const float* aW_f = (const float*)d_in[22];
    const float* ab_f = (const float*)d_in[23];
    const float* aW_r = (const float*)d_in[24];
    const float* ab_r = (const float*)d_in[25];
    const float* Wfr = (const float*)d_in[26];
    const float* bfr = (const float*)d_in[27];
    const float* Wro = (const float*)d_in[28];
    const float* bro = (const float*)d_in[29];
    float* outp = (float*)d_out;

    // ---- workspace carve (~69 MB) ----
    float* fw = (float*)d_ws;
    size_t fo = 0;
    float* xl    = fw + fo; fo += (size_t)NN * D1;   // xl1 then xl2
    float* xr_   = fw + fo; fo += (size_t)NN * D1;   // xr1 then xr2
    float* hbuf  = fw + fo; fo += (size_t)NN * D1;   // h, later reused as hi
    float* pemb  = fw + fo; fo += (size_t)NN * EMBD;
    float* attr1 = fw + fo; fo += (size_t)NATTR * D1;
    float* attr2 = fw + fo; fo += (size_t)NATTR * D1;
    float* mee1  = fw + fo; fo += D1;
    float* mee2  = fw + fo; fo += (size_t)NA * D1;
    float* frame_x = fw + fo; fo += D1;
    float* role_x  = fw + fo; fo += (size_t)NA * D1;
    float* part  = fw + fo; fo += (size_t)AGG_NB * 3 * D1;
    float* kf = fw + fo; fo += 64;
    float* vf = fw + fo; fo += 64;
    float* kr = fw + fo; fo += 512;
    float* qr = fw + fo; fo += 512;
    float* vr = fw + fo; fo += 512;
    float* outf = fw + fo; fo += 64;
    float* outr = fw + fo; fo += 512;
    float* flog = fw + fo; fo += 1504;
    int* iw = (int*)(fw + fo);
    int* row_ptr  = iw;            iw += NN + 1;
    int* cursor   = iw;            iw += NN;      // also used as in-degree counts
    int* csr_src  = iw;            iw += NE;
    int* csr_attr = iw;            iw += NE;
    unsigned* maskA = (unsigned*)iw; iw += NN;
    unsigned* maskB = (unsigned*)iw; iw += NN;
    unsigned* hist  = (unsigned*)iw; iw += 9 * 64;

    // ---- stage 0: gathers, tables, CSR ----
    k_gather_pemb<<<(NN * (EMBD / 4) + 255) / 256, 256, 0, stream>>>(node_pred, pred_emb, pemb);
    k_attr_ee<<<128, 512, 0, stream>>>(pred_emb, We1, We2, attr1, attr2);
    hipMemsetAsync(cursor, 0, sizeof(int) * NN, stream);
    k_indeg<<<256, 256, 0, stream>>>(e_dst, cursor);
    k_scan<<<1, 1024, 0, stream>>>(cursor, row_ptr, cursor);
    k_scatter<<<256, 256, 0, stream>>>(e_src, e_dst, edge_attr, cursor, csr_src, csr_attr);

    // ---- xl1/xr1 GEMMs ----
    dim3 gg(D1 / 128, (NN + 127) / 128);
    k_gemm<<<gg, 256, 0, stream>>>(pemb, Wl1, xl,  NN, EMBD, D1);
    k_gemm<<<gg, 256, 0, stream>>>(pemb, Wr1, xr_, NN, EMBD, D1);

    // ---- k-hop masks (3 hops, double-buffered; final in maskB) ----
    hipMemsetAsync(maskA, 0, sizeof(unsigned) * NN, stream);
    k_mask_seed<<<1, 64, 0, stream>>>(arg_nodes, maskA);
    hipMemsetAsync(maskB, 0, sizeof(unsigned) * NN, stream);
    k_prop<<<256, 256, 0, stream>>>(maskA, maskB, e_src, e_dst);
    hipMemsetAsync(maskA, 0, sizeof(unsigned) * NN, stream);
    k_prop<<<256, 256, 0, stream>>>(maskB, maskA, e_src, e_dst);
    hipMemsetAsync(maskB, 0, sizeof(unsigned) * NN, stream);
    k_prop<<<256, 256, 0, stream>>>(maskA, maskB, e_src, e_dst);

    // ---- histograms + mean edge embeddings ----
    hipMemsetAsync(hist, 0, sizeof(unsigned) * 9 * 64, stream);
    k_hist<<<256, 256, 0, stream>>>(e_src, e_dst, edge_attr, maskB, hist);
    k_mean_ee<<<9, 512, 0, stream>>>(hist, pred_emb, We1, We2, mee1, mee2);

    // ---- GAT layer 1 (full graph) -> h ----
    k_gat<<<NN, 256, 0, stream>>>(xl, xr_, attr1, mee1, att1, b1,
                                  row_ptr, csr_src, csr_attr, nullptr, 0, hbuf);
    k_aggr_partial<<<AGG_NB, 512, 0, stream>>>(hbuf, nullptr, 0, part);
    k_aggr_combine<<<1, 512, 0, stream>>>(part, AGG_NB, frame_x);

    // ---- xl2/xr2 GEMMs (consume h; then h buffer becomes hi) ----
    k_gemm<<<gg, 256, 0, stream>>>(hbuf, Wl2, xl,  NN, D1, D1);
    k_gemm<<<gg, 256, 0, stream>>>(hbuf, Wr2, xr_, NN, D1, D1);

    // ---- 8 masked GAT-2 passes + role aggregation ----
    for (int i = 0; i < NA; ++i) {
        k_gat<<<NN, 256, 0, stream>>>(xl, xr_, attr2, mee2 + (size_t)i * D1, att2, b2,
                                      row_ptr, csr_src, csr_attr, maskB, i, hbuf);
        k_aggr_partial<<<AGG_NB, 512, 0, stream>>>(hbuf, maskB, i, part);
        k_aggr_combine<<<1, 512, 0, stream>>>(part, AGG_NB, role_x + (size_t)i * D1);
    }

    // ---- HGT + heads ----
    k_hgt_a<<<26, 64, 0, stream>>>(frame_x, role_x, kqv_f, kqvb_f, kqv_r, kqvb_r,
                                   kf, vf, kr, qr, vr);
    k_hgt_b<<<1, 512, 0, stream>>>(kf, vf, kr, qr, vr, a_rel, m_rel, p_rel,
                                   aW_f, ab_f, aW_r, ab_r, outf, outr);
    k_frame_logits<<<(NFR + 255) / 256, 256, 0, stream>>>(outf, Wfr, bfr, flog);
    k_frame_lsm<<<1, 512, 0, stream>>>(flog, outp);
    k_roles<<<1, 512, 0, stream>>>(outr, Wro, bro, outp);
}

// Round 2
// 1119.659 us; speedup vs baseline: 1.1908x; 1.1908x over previous
//
#include <hip/hip_runtime.h>
#include <cfloat>
#include <cmath>

static constexpr int NN   = 10000;
static constexpr int NE   = 160000;
static constexpr int NA   = 8;
static constexpr int D1   = 512;
static constexpr int EMBD = 128;
static constexpr int NATTR= 64;
static constexpr int OUTD = 64;
static constexpr int NFR  = 1500;
static constexpr int AGG_NB = 64;

typedef short bf16x8 __attribute__((ext_vector_type(8)));
typedef float f32x4  __attribute__((ext_vector_type(4)));

__device__ __forceinline__ float b2f(unsigned short u) {
    union { unsigned u; float f; } v; v.u = ((unsigned)u) << 16; return v.f;
}
__device__ __forceinline__ unsigned short f2b(float f) {
    union { float f; unsigned u; } v; v.f = f;
    unsigned r = v.u + 0x7FFFu + ((v.u >> 16) & 1u);
    return (unsigned short)(r >> 16);
}

// ---------------- cast fp32 -> bf16 (vectorized) ----------------
__global__ void k_cast4(const float* __restrict__ src, unsigned short* __restrict__ dst, int n4) {
    int i = blockIdx.x * blockDim.x + threadIdx.x;
    if (i >= n4) return;
    float4 v = ((const float4*)src)[i];
    ushort4 o; o.x = f2b(v.x); o.y = f2b(v.y); o.z = f2b(v.z); o.w = f2b(v.w);
    ((ushort4*)dst)[i] = o;
}

// ---------------- gather p_emb = pred_emb[node_pred] -> bf16 ----------------
__global__ void k_gather_pemb(const int* __restrict__ node_pred,
                              const float* __restrict__ pred_emb,
                              unsigned short* __restrict__ pemb) {
    int idx = blockIdx.x * blockDim.x + threadIdx.x;   // NN * 32 float4
    int total = NN * (EMBD / 4);
    if (idx >= total) return;
    int n = idx >> 5, j = idx & 31;
    float4 v = ((const float4*)(pred_emb + (size_t)node_pred[n] * EMBD))[j];
    ushort4 o; o.x = f2b(v.x); o.y = f2b(v.y); o.z = f2b(v.z); o.w = f2b(v.w);
    ((ushort4*)(pemb + (size_t)n * EMBD))[j] = o;
}

// ---------------- attr tables (bf16 out) ----------------
__global__ void k_attr_ee(const float* __restrict__ pred_emb,
                          const float* __restrict__ We1, const float* __restrict__ We2,
                          unsigned short* __restrict__ t1, unsigned short* __restrict__ t2) {
    int a = blockIdx.x & 63;
    int which = blockIdx.x >> 6;
    const float* We = which ? We2 : We1;
    unsigned short* out = which ? t2 : t1;
    __shared__ float row[EMBD];
    if (threadIdx.x < EMBD) row[threadIdx.x] = pred_emb[a * EMBD + threadIdx.x];
    __syncthreads();
    int c = threadIdx.x;   // 512 threads
    float acc = 0.f;
    for (int k = 0; k < EMBD; ++k) acc += row[k] * We[k * D1 + c];
    out[a * D1 + c] = f2b(acc);
}

// ---------------- CSR build ----------------
__global__ void k_indeg(const int* __restrict__ dst, int* __restrict__ counts) {
    int stride = gridDim.x * blockDim.x;
    for (int e = blockIdx.x * blockDim.x + threadIdx.x; e < NE; e += stride)
        atomicAdd(&counts[dst[e]], 1);
}

__global__ __launch_bounds__(1024) void k_scan(const int* __restrict__ counts,
                                               int* __restrict__ row_ptr,
                                               int* __restrict__ cursor) {
    __shared__ int s[1024];
    __shared__ int base_s;
    int t = threadIdx.x;
    if (t == 0) base_s = 0;
    __syncthreads();
    for (int c0 = 0; c0 < NN; c0 += 1024) {
        int v = (c0 + t < NN) ? counts[c0 + t] : 0;
        s[t] = v; __syncthreads();
        for (int off = 1; off < 1024; off <<= 1) {
            int add = (t >= off) ? s[t - off] : 0;
            __syncthreads();
            s[t] += add;
            __syncthreads();
        }
        int base = base_s;
        int excl = base + s[t] - v;
        if (c0 + t < NN) { row_ptr[c0 + t] = excl; cursor[c0 + t] = excl; }
        __syncthreads();
        if (t == 0) base_s = base + s[1023];
        __syncthreads();
    }
    if (t == 0) row_ptr[NN] = base_s;
}

__global__ void k_scatter(const int* __restrict__ src, const int* __restrict__ dst,
                          const int* __restrict__ attr, int* __restrict__ cursor,
                          int* __restrict__ csr_src, int* __restrict__ csr_attr) {
    int stride = gridDim.x * blockDim.x;
    for (int e = blockIdx.x * blockDim.x + threadIdx.x; e < NE; e += stride) {
        int pos = atomicAdd(&cursor[dst[e]], 1);
        csr_src[pos] = src[e];
        csr_attr[pos] = attr[e];
    }
}

// ---------------- k-hop masks ----------------
__global__ void k_mask_seed(const int* __restrict__ arg_nodes, unsigned* __restrict__ mask) {
    if (threadIdx.x < NA) atomicOr(&mask[arg_nodes[threadIdx.x]], 1u << threadIdx.x);
}

__global__ void k_prop(const unsigned* __restrict__ oldm, unsigned* __restrict__ newm,
                       const int* __restrict__ src, const int* __restrict__ dst) {
    int stride = gridDim.x * blockDim.x;
    int t0 = blockIdx.x * blockDim.x + threadIdx.x;
    for (int n = t0; n < NN; n += stride) atomicOr(&newm[n], oldm[n]);
    for (int e = t0; e < NE; e += stride) {
        unsigned v = oldm[dst[e]];
        if (v) atomicOr(&newm[src[e]], v);
    }
}

// ---------------- attr histogram of kept edges ----------------
__global__ void k_hist(const int* __restrict__ src, const int* __restrict__ dst,
                       const int* __restrict__ attr, const unsigned* __restrict__ mask,
                       unsigned* __restrict__ hist) {
    __shared__ unsigned lh[9 * 64];
    for (int i = threadIdx.x; i < 9 * 64; i += blockDim.x) lh[i] = 0;
    __syncthreads();
    int stride = gridDim.x * blockDim.x;
    for (int e = blockIdx.x * blockDim.x + threadIdx.x; e < NE; e += stride) {
        int a = attr[e] & 63;
        atomicAdd(&lh[a], 1u);
        unsigned bits = mask[src[e]] & mask[dst[e]];
        while (bits) {
            int i = __ffs(bits) - 1;
            bits &= bits - 1;
            atomicAdd(&lh[(1 + i) * 64 + a], 1u);
        }
    }
    __syncthreads();
    for (int i = threadIdx.x; i < 9 * 64; i += blockDim.x)
        if (lh[i]) atomicAdd(&hist[i], lh[i]);
}

// ---------------- mean edge embedding tables (bf16 out) ----------------
__global__ __launch_bounds__(512) void k_mean_ee(const unsigned* __restrict__ hist,
                                                 const float* __restrict__ pred_emb,
                                                 const float* __restrict__ We1,
                                                 const float* __restrict__ We2,
                                                 unsigned short* __restrict__ mee1,
                                                 unsigned short* __restrict__ mee2) {
    int g = blockIdx.x;  // 0=full/We1, 1..8 = masks/We2
    const float* We = (g == 0) ? We1 : We2;
    unsigned short* out = (g == 0) ? mee1 : (mee2 + (g - 1) * D1);
    __shared__ float cnt[64];
    __shared__ float me[EMBD];
    __shared__ float tot_s;
    if (threadIdx.x < 64) cnt[threadIdx.x] = (float)hist[g * 64 + threadIdx.x];
    __syncthreads();
    if (threadIdx.x == 0) {
        float tt = 0.f;
        for (int a = 0; a < 64; ++a) tt += cnt[a];
        tot_s = fmaxf(tt, 1.0f);
    }
    __syncthreads();
    if (threadIdx.x < EMBD) {
        float acc = 0.f;
        for (int a = 0; a < 64; ++a) acc += cnt[a] * pred_emb[a * EMBD + threadIdx.x];
        me[threadIdx.x] = acc / tot_s;
    }
    __syncthreads();
    int c = threadIdx.x;
    float acc = 0.f;
    for (int k = 0; k < EMBD; ++k) acc += me[k] * We[k * D1 + c];
    out[c] = f2b(acc);
}

// ---------------- bf16 MFMA GEMM: C[M,N]=A[M,K]@B[K,N], 64x64 tile, 4 waves ----------------
__global__ __launch_bounds__(256) void k_gemm_bf(const unsigned short* __restrict__ A,
                                                 const unsigned short* __restrict__ B,
                                                 unsigned short* __restrict__ C,
                                                 int M, int K, int N) {
    __shared__ unsigned short As[64][40];   // [m][k], stride 80B (16B aligned rows)
    __shared__ unsigned short Bs[64][40];   // [n][k]
    int tid = threadIdx.x;
    int wave = tid >> 6, lane = tid & 63;
    int bm = blockIdx.y * 64, bn = blockIdx.x * 64;
    int wr = (wave >> 1) * 32, wc = (wave & 1) * 32;
    f32x4 zero = {0.f, 0.f, 0.f, 0.f};
    f32x4 acc[2][2] = {{zero, zero}, {zero, zero}};
    for (int k0 = 0; k0 < K; k0 += 32) {
        // A tile 64x32 (ushort2 per thread x4)
#pragma unroll
        for (int i = 0; i < 4; ++i) {
            int idx = tid + 256 * i;            // 0..1023
            int row = idx >> 4, kp = (idx & 15) * 2;
            unsigned v = 0;
            if (bm + row < M) v = *(const unsigned*)&A[(size_t)(bm + row) * K + k0 + kp];
            *(unsigned*)&As[row][kp] = v;
        }
        // B tile 32x64 -> transposed Bs[n][k]
#pragma unroll
        for (int i = 0; i < 8; ++i) {
            int idx = tid + 256 * i;            // 0..2047
            int k = idx >> 6, n = idx & 63;
            Bs[n][k] = B[(size_t)(k0 + k) * N + bn + n];
        }
        __syncthreads();
        int r = lane & 15, kb = (lane >> 4) * 8;
        bf16x8 a0 = *(const bf16x8*)&As[wr + r][kb];
        bf16x8 a1 = *(const bf16x8*)&As[wr + 16 + r][kb];
        bf16x8 b0 = *(const bf16x8*)&Bs[wc + r][kb];
        bf16x8 b1 = *(const bf16x8*)&Bs[wc + 16 + r][kb];
        acc[0][0] = __builtin_amdgcn_mfma_f32_16x16x32_bf16(a0, b0, acc[0][0], 0, 0, 0);
        acc[0][1] = __builtin_amdgcn_mfma_f32_16x16x32_bf16(a0, b1, acc[0][1], 0, 0, 0);
        acc[1][0] = __builtin_amdgcn_mfma_f32_16x16x32_bf16(a1, b0, acc[1][0], 0, 0, 0);
        acc[1][1] = __builtin_amdgcn_mfma_f32_16x16x32_bf16(a1, b1, acc[1][1], 0, 0, 0);
        __syncthreads();
    }
    // C/D layout: col = lane&15, row = (lane>>4)*4 + q
    int cr = (lane >> 4) * 4, cc = lane & 15;
#pragma unroll
    for (int i = 0; i < 2; ++i)
#pragma unroll
        for (int j = 0; j < 2; ++j)
#pragma unroll
            for (int q = 0; q < 4; ++q) {
                int row = bm + wr + i * 16 + cr + q;
                int col = bn + wc + j * 16 + cc;
                if (row < M) C[(size_t)row * N + col] = f2b(acc[i][j][q]);
            }
}

// ---------------- GATv2 (bf16 operands, fp32 math), online softmax ----------------
__global__ __launch_bounds__(256) void k_gat(const unsigned short* __restrict__ xl,
                                             const unsigned short* __restrict__ xr,
                                             const unsigned short* __restrict__ attr_ee,
                                             const unsigned short* __restrict__ mean_ee,
                                             const float* __restrict__ att,
                                             const float* __restrict__ bias,
                                             const int* __restrict__ row_ptr,
                                             const int* __restrict__ csr_src,
                                             const int* __restrict__ csr_attr,
                                             const unsigned* __restrict__ mask, int bit,
                                             unsigned short* __restrict__ out) {
    int n = blockIdx.x;
    if (mask && !((mask[n] >> bit) & 1u)) return;
    int t = threadIdx.x;
    int c = 2 * t;                       // wave w covers channels [128w,128w+128) = head w
    unsigned vr_ = *(const unsigned*)&xr[(size_t)n * D1 + c];
    float xr0 = b2f((unsigned short)(vr_ & 0xffff));
    float xr1 = b2f((unsigned short)(vr_ >> 16));
    float a0 = att[c], a1 = att[c + 1];
    float m = -FLT_MAX, den = 0.f, acc0 = 0.f, acc1 = 0.f;
    int pend = row_ptr[n + 1];
    for (int p = row_ptr[n]; p <= pend; ++p) {   // p==pend: self-loop
        int s;
        const unsigned short* ee;
        if (p == pend) { s = n; ee = mean_ee; }
        else {
            s = csr_src[p];
            if (mask && !((mask[s] >> bit) & 1u)) continue;
            ee = attr_ee + (size_t)(csr_attr[p] & 63) * D1;
        }
        unsigned vs = *(const unsigned*)&xl[(size_t)s * D1 + c];
        unsigned ve = *(const unsigned*)&ee[c];
        float xs0 = b2f((unsigned short)(vs & 0xffff));
        float xs1 = b2f((unsigned short)(vs >> 16));
        float z0 = xs0 + xr0 + b2f((unsigned short)(ve & 0xffff));
        float z1 = xs1 + xr1 + b2f((unsigned short)(ve >> 16));
        z0 = (z0 > 0.f) ? z0 : 0.2f * z0;
        z1 = (z1 > 0.f) ? z1 : 0.2f * z1;
        float ps = z0 * a0 + z1 * a1;
#pragma unroll
        for (int off = 32; off; off >>= 1) ps += __shfl_xor(ps, off, 64);
        float nm = fmaxf(m, ps);
        float sc = __expf(m - nm);
        float w  = __expf(ps - nm);
        den  = den * sc + w;
        acc0 = acc0 * sc + w * xs0;
        acc1 = acc1 * sc + w * xs1;
        m = nm;
    }
    float inv = 1.f / (den + 1e-16f);
    unsigned short o0 = f2b(acc0 * inv + bias[c]);
    unsigned short o1 = f2b(acc1 * inv + bias[c + 1]);
    *(unsigned*)&out[(size_t)n * D1 + c] = ((unsigned)o1 << 16) | o0;
}

// ---------------- column softmax-aggregation over nodes (bf16 input) ----------------
__global__ __launch_bounds__(512) void k_aggr_partial(const unsigned short* __restrict__ x,
                                                      const unsigned* __restrict__ mask, int bit,
                                                      float* __restrict__ part) {
    int c = threadIdx.x;
    int rows = (NN + gridDim.x - 1) / gridDim.x;
    int r0 = blockIdx.x * rows;
    int r1 = min(NN, r0 + rows);
    float m = -FLT_MAX, den = 0.f, num = 0.f;
    for (int r = r0; r < r1; ++r) {
        if (mask && !((mask[r] >> bit) & 1u)) continue;
        float v = b2f(x[(size_t)r * D1 + c]);
        float nm = fmaxf(m, v);
        float sc = __expf(m - nm);
        float w  = __expf(v - nm);
        den = den * sc + w;
        num = num * sc + w * v;
        m = nm;
    }
    part[(blockIdx.x * 3 + 0) * D1 + c] = m;
    part[(blockIdx.x * 3 + 1) * D1 + c] = den;
    part[(blockIdx.x * 3 + 2) * D1 + c] = num;
}

__global__ __launch_bounds__(512) void k_aggr_combine(const float* __restrict__ part, int nb,
                                                      float* __restrict__ out) {
    int c = threadIdx.x;
    float M = -FLT_MAX;
    for (int b = 0; b < nb; ++b) M = fmaxf(M, part[(b * 3) * D1 + c]);
    float den = 0.f, num = 0.f;
    for (int b = 0; b < nb; ++b) {
        float sc = __expf(part[(b * 3 + 0) * D1 + c] - M);
        den += part[(b * 3 + 1) * D1 + c] * sc;
        num += part[(b * 3 + 2) * D1 + c] * sc;
    }
    out[c] = num / den;
}

// ---------------- HGT stage A ----------------
__global__ void k_hgt_a(const float* __restrict__ frame_x, const float* __restrict__ role_x,
                        const float* __restrict__ kqv_f, const float* __restrict__ kqvb_f,
                        const float* __restrict__ kqv_r, const float* __restrict__ kqvb_r,
                        float* __restrict__ kf, float* __restrict__ vf,
                        float* __restrict__ kr, float* __restrict__ qr, float* __restrict__ vr) {
    int b = blockIdx.x, j = threadIdx.x;
    const float *x, *W, *bi;
    float* out;
    if (b == 0)      { x = frame_x;               W = kqv_f;                    bi = kqvb_f;            out = kf; }
    else if (b == 1) { x = frame_x;               W = kqv_f + 2 * D1 * OUTD;    bi = kqvb_f + 2 * OUTD; out = vf; }
    else if (b < 10) { int i = b - 2;  x = role_x + i * D1; W = kqv_r;                 bi = kqvb_r;            out = kr + i * OUTD; }
    else if (b < 18) { int i = b - 10; x = role_x + i * D1; W = kqv_r + D1 * OUTD;     bi = kqvb_r + OUTD;     out = qr + i * OUTD; }
    else             { int i = b - 18; x = role_x + i * D1; W = kqv_r + 2 * D1 * OUTD; bi = kqvb_r + 2 * OUTD; out = vr + i * OUTD; }
    float acc = bi[j];
    for (int k = 0; k < D1; ++k) acc += x[k] * W[k * OUTD + j];
    out[j] = acc;
}

// ---------------- HGT stage B ----------------
__global__ __launch_bounds__(512) void k_hgt_b(const float* __restrict__ kf_g,
                                               const float* __restrict__ vf_g,
                                               const float* __restrict__ kr_g,
                                               const float* __restrict__ qr_g,
                                               const float* __restrict__ vr_g,
                                               const float* __restrict__ a_rel,
                                               const float* __restrict__ m_rel,
                                               const float* __restrict__ p_rel,
                                               const float* __restrict__ aW_f,
                                               const float* __restrict__ ab_f,
                                               const float* __restrict__ aW_r,
                                               const float* __restrict__ ab_r,
                                               float* __restrict__ out_f,
                                               float* __restrict__ out_r) {
    __shared__ float kf[64], vf[64], kr[512], qr[512], vr[512];
    __shared__ float ka1[64], vfm1[64], aggf[64], geluf[64];
    __shared__ float kra2[512], vrm[512], gelur[512];
    __shared__ float al[8][2];
    int t = threadIdx.x;
    if (t < 64) { kf[t] = kf_g[t]; vf[t] = vf_g[t]; }
    kr[t] = kr_g[t]; qr[t] = qr_g[t]; vr[t] = vr_g[t];
    __syncthreads();
    int i = t >> 6, j = t & 63;
    {
        float acc1 = 0.f, acc2 = 0.f;
        for (int k = 0; k < 64; ++k) {
            acc1 += kr[i * 64 + k] * a_rel[2 * 4096 + k * 64 + j];
            acc2 += vr[i * 64 + k] * m_rel[2 * 4096 + k * 64 + j];
        }
        kra2[t] = acc1; vrm[t] = acc2;
    }
    if (t < 64) {
        float acc1 = 0.f, acc2 = 0.f, acc3 = 0.f;
        for (int k = 0; k < 64; ++k) {
            acc1 += kf[k] * a_rel[1 * 4096 + k * 64 + j];
            acc2 += vf[k] * m_rel[0 * 4096 + k * 64 + j];
            acc3 += vf[k] * m_rel[1 * 4096 + k * 64 + j];
        }
        ka1[j] = acc1; aggf[j] = acc2; vfm1[j] = acc3;
    }
    __syncthreads();
    if (t < 8) {
        const float sq = 0.125f;
        float p1 = p_rel[1], p2 = p_rel[2];
        float sfr = 0.f, srr = 0.f;
        for (int d = 0; d < 64; ++d) {
            sfr += qr[t * 64 + d] * ka1[d];
            srr += qr[t * 64 + d] * kra2[t * 64 + d];
        }
        sfr *= sq * p1; srr *= sq * p2;
        float mx = fmaxf(sfr, srr);
        float e0 = __expf(sfr - mx), e1 = __expf(srr - mx);
        float inv = 1.f / (e0 + e1);
        al[t][0] = e0 * inv; al[t][1] = e1 * inv;
    }
    __syncthreads();
    {
        float av = al[i][0] * vfm1[j] + al[i][1] * vrm[t];
        gelur[t] = 0.5f * av * (1.f + erff(av * 0.70710678118654752f));
    }
    if (t < 64) geluf[t] = 0.5f * aggf[t] * (1.f + erff(aggf[t] * 0.70710678118654752f));
    __syncthreads();
    {
        float acc = ab_r[j];
        for (int k = 0; k < 64; ++k) acc += gelur[i * 64 + k] * aW_r[k * 64 + j];
        out_r[t] = acc;
    }
    if (t < 64) {
        float acc = ab_f[j];
        for (int k = 0; k < 64; ++k) acc += geluf[k] * aW_f[k * 64 + j];
        out_f[j] = acc;
    }
}

// ---------------- frame logits + log_softmax ----------------
__global__ void k_frame_logits(const float* __restrict__ out_f, const float* __restrict__ Wfr,
                               const float* __restrict__ bfr, float* __restrict__ flog) {
    __shared__ float xf[64];
    if (threadIdx.x < 64) xf[threadIdx.x] = out_f[threadIdx.x];
    __syncthreads();
    int j = blockIdx.x * blockDim.x + threadIdx.x;
    if (j >= NFR) return;
    float acc = bfr[j];
    for (int k = 0; k < 64; ++k) acc += xf[k] * Wfr[k * NFR + j];
    flog[j] = acc;
}

__global__ __launch_bounds__(512) void k_frame_lsm(const float* __restrict__ flog,
                                                   float* __restrict__ outp) {
    __shared__ float red[512];
    int t = threadIdx.x;
    float m = -FLT_MAX;
    for (int j = t; j < NFR; j += 512) m = fmaxf(m, flog[j]);
    red[t] = m; __syncthreads();
    for (int off = 256; off; off >>= 1) { if (t < off) red[t] = fmaxf(red[t], red[t + off]); __syncthreads(); }
    float M = red[0]; __syncthreads();
    float s = 0.f;
    for (int j = t; j < NFR; j += 512) s += __expf(flog[j] - M);
    red[t] = s; __syncthreads();
    for (int off = 256; off; off >>= 1) { if (t < off) red[t] += red[t + off]; __syncthreads(); }
    float lse = M + logf(red[0]);
    for (int j = t; j < NFR; j += 512) outp[j] = flog[j] - lse;
}

__global__ __launch_bounds__(512) void k_roles(const float* __restrict__ out_r,
                                               const float* __restrict__ Wro,
                                               const float* __restrict__ bro,
                                               float* __restrict__ outp) {
    int t = threadIdx.x;
    int i = t >> 6, j = t & 63;
    __shared__ float xr_s[512];
    xr_s[t] = out_r[t];
    __syncthreads();
    float acc = bro[j];
    for (int k = 0; k < 64; ++k) acc += xr_s[i * 64 + k] * Wro[k * 64 + j];
    float m = acc;
#pragma unroll
    for (int off = 32; off; off >>= 1) m = fmaxf(m, __shfl_xor(m, off, 64));
    float e = __expf(acc - m);
    float s = e;
#pragma unroll
    for (int off = 32; off; off >>= 1) s += __shfl_xor(s, off, 64);
    outp[NFR + t] = acc - m - logf(s);
}

// =====================================================================
extern "C" void kernel_launch(void* const* d_in, const int* in_sizes, int n_in,
                              void* d_out, int out_size, void* d_ws, size_t ws_size,
                              hipStream_t stream) {
    const int* node_pred  = (const int*)d_in[0];
    const int* edge_index = (const int*)d_in[1];
    const int* e_src = edge_index;
    const int* e_dst = edge_index + NE;
    const int* edge_attr  = (const int*)d_in[2];
    const int* arg_nodes  = (const int*)d_in[3];
    const float* pred_emb = (const float*)d_in[4];
    const float* Wl1 = (const float*)d_in[5];
    const float* Wr1 = (const float*)d_in[6];
    const float* We1 = (const float*)d_in[7];
    const float* att1 = (const float*)d_in[8];
    const float* b1  = (const float*)d_in[9];
    const float* Wl2 = (const float*)d_in[10];
    const float* Wr2 = (const float*)d_in[11];
    const float* We2 = (const float*)d_in[12];
    const float* att2 = (const float*)d_in[13];
    const float* b2  = (const float*)d_in[14];
    const float* kqv_f  = (const float*)d_in[15];
    const float* kqvb_f = (const float*)d_in[16];
    const float* kqv_r  = (const float*)d_in[17];
    const float* kqvb_r = (const float*)d_in[18];
    const float* a_rel  = (const float*)d_in[19];
    const float* m_rel  = (const float*)d_in[20];
    const float* p_rel  = (const float*)d_in[21];
    const float* aW_f = (const float*)d_in[22];
    const float* ab_f = (const float*)d_in[23];
    const float* aW_r = (const float*)d_in[24];
    const float* ab_r = (const float*)d_in[25];
    const float* Wfr = (const float*)d_in[26];
    const float* bfr = (const float*)d_in[27];
    const float* Wro = (const float*)d_in[28];
    const float* bro = (const float*)d_in[29];
    float* outp = (float*)d_out;

    // ---- workspace carve (byte-based, 256B aligned chunks) ----
    char* base = (char*)d_ws;
    size_t off = 0;
    auto alloc = [&](size_t bytes) -> void* {
        void* p = base + off;
        off += (bytes + 255) & ~(size_t)255;
        return p;
    };
    // fp32 regions
    float* frame_x = (float*)alloc(D1 * 4);
    float* role_x  = (float*)alloc(NA * D1 * 4);
    float* part    = (float*)alloc((size_t)AGG_NB * 3 * D1 * 4);
    float* kf   = (float*)alloc(64 * 4);
    float* vf   = (float*)alloc(64 * 4);
    float* kr   = (float*)alloc(512 * 4);
    float* qr   = (float*)alloc(512 * 4);
    float* vr   = (float*)alloc(512 * 4);
    float* outf = (float*)alloc(64 * 4);
    float* outr = (float*)alloc(512 * 4);
    float* flog = (float*)alloc(NFR * 4);
    // int regions
    int* row_ptr  = (int*)alloc((NN + 1) * 4);
    int* cursor   = (int*)alloc(NN * 4);
    int* csr_src  = (int*)alloc((size_t)NE * 4);
    int* csr_attr = (int*)alloc((size_t)NE * 4);
    unsigned* maskA = (unsigned*)alloc(NN * 4);
    unsigned* maskB = (unsigned*)alloc(NN * 4);
    unsigned* hist  = (unsigned*)alloc(9 * 64 * 4);
    // bf16 regions
    unsigned short* xl    = (unsigned short*)alloc((size_t)NN * D1 * 2);
    unsigned short* xr_   = (unsigned short*)alloc((size_t)NN * D1 * 2);
    unsigned short* hbuf  = (unsigned short*)alloc((size_t)NN * D1 * 2);  // h, then hi
    unsigned short* pemb  = (unsigned short*)alloc((size_t)NN * EMBD * 2);
    unsigned short* wl1b  = (unsigned short*)alloc((size_t)EMBD * D1 * 2);
    unsigned short* wr1b  = (unsigned short*)alloc((size_t)EMBD * D1 * 2);
    unsigned short* wl2b  = (unsigned short*)alloc((size_t)D1 * D1 * 2);
    unsigned short* wr2b  = (unsigned short*)alloc((size_t)D1 * D1 * 2);
    unsigned short* attr1 = (unsigned short*)alloc((size_t)NATTR * D1 * 2);
    unsigned short* attr2 = (unsigned short*)alloc((size_t)NATTR * D1 * 2);
    unsigned short* mee1  = (unsigned short*)alloc(D1 * 2);
    unsigned short* mee2  = (unsigned short*)alloc((size_t)NA * D1 * 2);

    // ---- stage 0: casts, gathers, tables, CSR ----
    k_cast4<<<(EMBD * D1 / 4 + 255) / 256, 256, 0, stream>>>(Wl1, wl1b, EMBD * D1 / 4);
    k_cast4<<<(EMBD * D1 / 4 + 255) / 256, 256, 0, stream>>>(Wr1, wr1b, EMBD * D1 / 4);
    k_cast4<<<(D1 * D1 / 4 + 255) / 256, 256, 0, stream>>>(Wl2, wl2b, D1 * D1 / 4);
    k_cast4<<<(D1 * D1 / 4 + 255) / 256, 256, 0, stream>>>(Wr2, wr2b, D1 * D1 / 4);
    k_gather_pemb<<<(NN * (EMBD / 4) + 255) / 256, 256, 0, stream>>>(node_pred, pred_emb, pemb);
    k_attr_ee<<<128, 512, 0, stream>>>(pred_emb, We1, We2, attr1, attr2);
    hipMemsetAsync(cursor, 0, sizeof(int) * NN, stream);
    k_indeg<<<256, 256, 0, stream>>>(e_dst, cursor);
    k_scan<<<1, 1024, 0, stream>>>(cursor, row_ptr, cursor);
    k_scatter<<<256, 256, 0, stream>>>(e_src, e_dst, edge_attr, cursor, csr_src, csr_attr);

    // ---- xl1/xr1 GEMMs (bf16 MFMA) ----
    dim3 gg(D1 / 64, (NN + 63) / 64);
    k_gemm_bf<<<gg, 256, 0, stream>>>(pemb, wl1b, xl,  NN, EMBD, D1);
    k_gemm_bf<<<gg, 256, 0, stream>>>(pemb, wr1b, xr_, NN, EMBD, D1);

    // ---- k-hop masks (3 hops, double-buffered; final in maskB) ----
    hipMemsetAsync(maskA, 0, sizeof(unsigned) * NN, stream);
    k_mask_seed<<<1, 64, 0, stream>>>(arg_nodes, maskA);
    hipMemsetAsync(maskB, 0, sizeof(unsigned) * NN, stream);
    k_prop<<<256, 256, 0, stream>>>(maskA, maskB, e_src, e_dst);
    hipMemsetAsync(maskA, 0, sizeof(unsigned) * NN, stream);
    k_prop<<<256, 256, 0, stream>>>(maskB, maskA, e_src, e_dst);
    hipMemsetAsync(maskB, 0, sizeof(unsigned) * NN, stream);
    k_prop<<<256, 256, 0, stream>>>(maskA, maskB, e_src, e_dst);

    // ---- histograms + mean edge embeddings ----
    hipMemsetAsync(hist, 0, sizeof(unsigned) * 9 * 64, stream);
    k_hist<<<256, 256, 0, stream>>>(e_src, e_dst, edge_attr, maskB, hist);
    k_mean_ee<<<9, 512, 0, stream>>>(hist, pred_emb, We1, We2, mee1, mee2);

    // ---- GAT layer 1 (full graph) -> h (bf16) ----
    k_gat<<<NN, 256, 0, stream>>>(xl, xr_, attr1, mee1, att1, b1,
                                  row_ptr, csr_src, csr_attr, nullptr, 0, hbuf);
    k_aggr_partial<<<AGG_NB, 512, 0, stream>>>(hbuf, nullptr, 0, part);
    k_aggr_combine<<<1, 512, 0, stream>>>(part, AGG_NB, frame_x);

    // ---- xl2/xr2 GEMMs ----
    k_gemm_bf<<<gg, 256, 0, stream>>>(hbuf, wl2b, xl,  NN, D1, D1);
    k_gemm_bf<<<gg, 256, 0, stream>>>(hbuf, wr2b, xr_, NN, D1, D1);

    // ---- 8 masked GAT-2 passes + role aggregation ----
    for (int i = 0; i < NA; ++i) {
        k_gat<<<NN, 256, 0, stream>>>(xl, xr_, attr2, mee2 + (size_t)i * D1, att2, b2,
                                      row_ptr, csr_src, csr_attr, maskB, i, hbuf);
        k_aggr_partial<<<AGG_NB, 512, 0, stream>>>(hbuf, maskB, i, part);
        k_aggr_combine<<<1, 512, 0, stream>>>(part, AGG_NB, role_x + (size_t)i * D1);
    }

    // ---- HGT + heads (fp32) ----
    k_hgt_a<<<26, 64, 0, stream>>>(frame_x, role_x, kqv_f, kqvb_f, kqv_r, kqvb_r,
                                   kf, vf, kr, qr, vr);
    k_hgt_b<<<1, 512, 0, stream>>>(kf, vf, kr, qr, vr, a_rel, m_rel, p_rel,
                                   aW_f, ab_f, aW_r, ab_r, outf, outr);
    k_frame_logits<<<(NFR + 255) / 256, 256, 0, stream>>>(outf, Wfr, bfr, flog);
    k_frame_lsm<<<1, 512, 0, stream>>>(flog, outp);
    k_roles<<<1, 512, 0, stream>>>(outr, Wro, bro, outp);
}

// Round 3
// 778.484 us; speedup vs baseline: 1.7127x; 1.4383x over previous
//
#include <hip/hip_runtime.h>
#include <cfloat>
#include <cmath>

static constexpr int NN   = 10000;
static constexpr int NE   = 160000;
static constexpr int NA   = 8;
static constexpr int D1   = 512;
static constexpr int EMBD = 128;
static constexpr int NATTR= 64;
static constexpr int OUTD = 64;
static constexpr int NFR  = 1500;
static constexpr int AGG_NB = 250;   // 250 blocks x 40 rows = 10000

typedef short bf16x8 __attribute__((ext_vector_type(8)));
typedef float f32x4  __attribute__((ext_vector_type(4)));

__device__ __forceinline__ float b2f(unsigned short u) {
    union { unsigned u; float f; } v; v.u = ((unsigned)u) << 16; return v.f;
}
__device__ __forceinline__ unsigned short f2b(float f) {
    union { float f; unsigned u; } v; v.f = f;
    unsigned r = v.u + 0x7FFFu + ((v.u >> 16) & 1u);
    return (unsigned short)(r >> 16);
}

// ---------------- cast fp32 -> bf16 ----------------
__global__ void k_cast4(const float* __restrict__ src, unsigned short* __restrict__ dst, int n4) {
    int i = blockIdx.x * blockDim.x + threadIdx.x;
    if (i >= n4) return;
    float4 v = ((const float4*)src)[i];
    ushort4 o; o.x = f2b(v.x); o.y = f2b(v.y); o.z = f2b(v.z); o.w = f2b(v.w);
    ((ushort4*)dst)[i] = o;
}

// ---------------- gather p_emb -> bf16 ----------------
__global__ void k_gather_pemb(const int* __restrict__ node_pred,
                              const float* __restrict__ pred_emb,
                              unsigned short* __restrict__ pemb) {
    int idx = blockIdx.x * blockDim.x + threadIdx.x;
    int total = NN * (EMBD / 4);
    if (idx >= total) return;
    int n = idx >> 5, j = idx & 31;
    float4 v = ((const float4*)(pred_emb + (size_t)node_pred[n] * EMBD))[j];
    ushort4 o; o.x = f2b(v.x); o.y = f2b(v.y); o.z = f2b(v.z); o.w = f2b(v.w);
    ((ushort4*)(pemb + (size_t)n * EMBD))[j] = o;
}

// ---------------- attr tables (bf16) ----------------
__global__ void k_attr_ee(const float* __restrict__ pred_emb,
                          const float* __restrict__ We1, const float* __restrict__ We2,
                          unsigned short* __restrict__ t1, unsigned short* __restrict__ t2) {
    int a = blockIdx.x & 63;
    int which = blockIdx.x >> 6;
    const float* We = which ? We2 : We1;
    unsigned short* out = which ? t2 : t1;
    __shared__ float row[EMBD];
    if (threadIdx.x < EMBD) row[threadIdx.x] = pred_emb[a * EMBD + threadIdx.x];
    __syncthreads();
    int c = threadIdx.x;
    float acc = 0.f;
    for (int k = 0; k < EMBD; ++k) acc += row[k] * We[k * D1 + c];
    out[a * D1 + c] = f2b(acc);
}

// ---------------- CSR build ----------------
__global__ void k_indeg(const int* __restrict__ dst, int* __restrict__ counts) {
    int stride = gridDim.x * blockDim.x;
    for (int e = blockIdx.x * blockDim.x + threadIdx.x; e < NE; e += stride)
        atomicAdd(&counts[dst[e]], 1);
}

__global__ __launch_bounds__(1024) void k_scan(const int* __restrict__ counts,
                                               int* __restrict__ row_ptr,
                                               int* __restrict__ cursor) {
    __shared__ int s[1024];
    __shared__ int base_s;
    int t = threadIdx.x;
    if (t == 0) base_s = 0;
    __syncthreads();
    for (int c0 = 0; c0 < NN; c0 += 1024) {
        int v = (c0 + t < NN) ? counts[c0 + t] : 0;
        s[t] = v; __syncthreads();
        for (int off = 1; off < 1024; off <<= 1) {
            int add = (t >= off) ? s[t - off] : 0;
            __syncthreads();
            s[t] += add;
            __syncthreads();
        }
        int base = base_s;
        int excl = base + s[t] - v;
        if (c0 + t < NN) { row_ptr[c0 + t] = excl; cursor[c0 + t] = excl; }
        __syncthreads();
        if (t == 0) base_s = base + s[1023];
        __syncthreads();
    }
    if (t == 0) row_ptr[NN] = base_s;
}

__global__ void k_scatter(const int* __restrict__ src, const int* __restrict__ dst,
                          const int* __restrict__ attr, int* __restrict__ cursor,
                          int* __restrict__ csr_src, int* __restrict__ csr_attr) {
    int stride = gridDim.x * blockDim.x;
    for (int e = blockIdx.x * blockDim.x + threadIdx.x; e < NE; e += stride) {
        int pos = atomicAdd(&cursor[dst[e]], 1);
        csr_src[pos] = src[e];
        csr_attr[pos] = attr[e];
    }
}

// ---------------- k-hop masks ----------------
__global__ void k_mask_seed(const int* __restrict__ arg_nodes, unsigned* __restrict__ mask) {
    if (threadIdx.x < NA) atomicOr(&mask[arg_nodes[threadIdx.x]], 1u << threadIdx.x);
}

__global__ void k_prop(const unsigned* __restrict__ oldm, unsigned* __restrict__ newm,
                       const int* __restrict__ src, const int* __restrict__ dst) {
    int stride = gridDim.x * blockDim.x;
    int t0 = blockIdx.x * blockDim.x + threadIdx.x;
    for (int n = t0; n < NN; n += stride) atomicOr(&newm[n], oldm[n]);
    for (int e = t0; e < NE; e += stride) {
        unsigned v = oldm[dst[e]];
        if (v) atomicOr(&newm[src[e]], v);
    }
}

// ---------------- attr histogram ----------------
__global__ void k_hist(const int* __restrict__ src, const int* __restrict__ dst,
                       const int* __restrict__ attr, const unsigned* __restrict__ mask,
                       unsigned* __restrict__ hist) {
    __shared__ unsigned lh[9 * 64];
    for (int i = threadIdx.x; i < 9 * 64; i += blockDim.x) lh[i] = 0;
    __syncthreads();
    int stride = gridDim.x * blockDim.x;
    for (int e = blockIdx.x * blockDim.x + threadIdx.x; e < NE; e += stride) {
        int a = attr[e] & 63;
        atomicAdd(&lh[a], 1u);
        unsigned bits = mask[src[e]] & mask[dst[e]];
        while (bits) {
            int i = __ffs(bits) - 1;
            bits &= bits - 1;
            atomicAdd(&lh[(1 + i) * 64 + a], 1u);
        }
    }
    __syncthreads();
    for (int i = threadIdx.x; i < 9 * 64; i += blockDim.x)
        if (lh[i]) atomicAdd(&hist[i], lh[i]);
}

// ---------------- mean edge embedding tables (bf16) ----------------
__global__ __launch_bounds__(512) void k_mean_ee(const unsigned* __restrict__ hist,
                                                 const float* __restrict__ pred_emb,
                                                 const float* __restrict__ We1,
                                                 const float* __restrict__ We2,
                                                 unsigned short* __restrict__ mee1,
                                                 unsigned short* __restrict__ mee2) {
    int g = blockIdx.x;
    const float* We = (g == 0) ? We1 : We2;
    unsigned short* out = (g == 0) ? mee1 : (mee2 + (g - 1) * D1);
    __shared__ float cnt[64];
    __shared__ float me[EMBD];
    __shared__ float tot_s;
    if (threadIdx.x < 64) cnt[threadIdx.x] = (float)hist[g * 64 + threadIdx.x];
    __syncthreads();
    if (threadIdx.x == 0) {
        float tt = 0.f;
        for (int a = 0; a < 64; ++a) tt += cnt[a];
        tot_s = fmaxf(tt, 1.0f);
    }
    __syncthreads();
    if (threadIdx.x < EMBD) {
        float acc = 0.f;
        for (int a = 0; a < 64; ++a) acc += cnt[a] * pred_emb[a * EMBD + threadIdx.x];
        me[threadIdx.x] = acc / tot_s;
    }
    __syncthreads();
    int c = threadIdx.x;
    float acc = 0.f;
    for (int k = 0; k < EMBD; ++k) acc += me[k] * We[k * D1 + c];
    out[c] = f2b(acc);
}

// ---------------- bf16 MFMA GEMM (64x64 tile) ----------------
__global__ __launch_bounds__(256) void k_gemm_bf(const unsigned short* __restrict__ A,
                                                 const unsigned short* __restrict__ B,
                                                 unsigned short* __restrict__ C,
                                                 int M, int K, int N) {
    __shared__ unsigned short As[64][40];
    __shared__ unsigned short Bs[64][40];
    int tid = threadIdx.x;
    int wave = tid >> 6, lane = tid & 63;
    int bm = blockIdx.y * 64, bn = blockIdx.x * 64;
    int wr = (wave >> 1) * 32, wc = (wave & 1) * 32;
    f32x4 zero = {0.f, 0.f, 0.f, 0.f};
    f32x4 acc[2][2] = {{zero, zero}, {zero, zero}};
    for (int k0 = 0; k0 < K; k0 += 32) {
#pragma unroll
        for (int i = 0; i < 4; ++i) {
            int idx = tid + 256 * i;
            int row = idx >> 4, kp = (idx & 15) * 2;
            unsigned v = 0;
            if (bm + row < M) v = *(const unsigned*)&A[(size_t)(bm + row) * K + k0 + kp];
            *(unsigned*)&As[row][kp] = v;
        }
#pragma unroll
        for (int i = 0; i < 8; ++i) {
            int idx = tid + 256 * i;
            int k = idx >> 6, n = idx & 63;
            Bs[n][k] = B[(size_t)(k0 + k) * N + bn + n];
        }
        __syncthreads();
        int r = lane & 15, kb = (lane >> 4) * 8;
        bf16x8 a0 = *(const bf16x8*)&As[wr + r][kb];
        bf16x8 a1 = *(const bf16x8*)&As[wr + 16 + r][kb];
        bf16x8 b0 = *(const bf16x8*)&Bs[wc + r][kb];
        bf16x8 b1 = *(const bf16x8*)&Bs[wc + 16 + r][kb];
        acc[0][0] = __builtin_amdgcn_mfma_f32_16x16x32_bf16(a0, b0, acc[0][0], 0, 0, 0);
        acc[0][1] = __builtin_amdgcn_mfma_f32_16x16x32_bf16(a0, b1, acc[0][1], 0, 0, 0);
        acc[1][0] = __builtin_amdgcn_mfma_f32_16x16x32_bf16(a1, b0, acc[1][0], 0, 0, 0);
        acc[1][1] = __builtin_amdgcn_mfma_f32_16x16x32_bf16(a1, b1, acc[1][1], 0, 0, 0);
        __syncthreads();
    }
    int cr = (lane >> 4) * 4, cc = lane & 15;
#pragma unroll
    for (int i = 0; i < 2; ++i)
#pragma unroll
        for (int j = 0; j < 2; ++j)
#pragma unroll
            for (int q = 0; q < 4; ++q) {
                int row = bm + wr + i * 16 + cr + q;
                int col = bn + wc + j * 16 + cc;
                if (row < M) C[(size_t)row * N + col] = f2b(acc[i][j][q]);
            }
}

// ---------------- full-graph GATv2, pair-ILP online softmax ----------------
__global__ __launch_bounds__(256) void k_gat(const unsigned short* __restrict__ xl,
                                             const unsigned short* __restrict__ xr,
                                             const unsigned short* __restrict__ attr_ee,
                                             const unsigned short* __restrict__ mean_ee,
                                             const float* __restrict__ att,
                                             const float* __restrict__ bias,
                                             const int* __restrict__ row_ptr,
                                             const int* __restrict__ csr_src,
                                             const int* __restrict__ csr_attr,
                                             unsigned short* __restrict__ out) {
    int n = blockIdx.x;
    int t = threadIdx.x;
    int c = 2 * t;
    unsigned vr_ = *(const unsigned*)&xr[(size_t)n * D1 + c];
    float xr0 = b2f((unsigned short)(vr_ & 0xffff));
    float xr1 = b2f((unsigned short)(vr_ >> 16));
    float a0 = att[c], a1 = att[c + 1];
    float m = -FLT_MAX, den = 0.f, acc0 = 0.f, acc1 = 0.f;
    int pstart = row_ptr[n], pend = row_ptr[n + 1];
    int items = pend - pstart + 1;     // +1 self-loop
    int it = 0;
    for (; it + 1 < items; it += 2) {
        int pA = pstart + it, pB = pstart + it + 1;
        // A is always a real edge; B may be the self-loop
        int sA = csr_src[pA];
        const unsigned short* eA = attr_ee + (size_t)(csr_attr[pA] & 63) * D1;
        int sB; const unsigned short* eB;
        if (pB == pend) { sB = n; eB = mean_ee; }
        else { sB = csr_src[pB]; eB = attr_ee + (size_t)(csr_attr[pB] & 63) * D1; }
        unsigned vsA = *(const unsigned*)&xl[(size_t)sA * D1 + c];
        unsigned veA = *(const unsigned*)&eA[c];
        unsigned vsB = *(const unsigned*)&xl[(size_t)sB * D1 + c];
        unsigned veB = *(const unsigned*)&eB[c];
        float xA0 = b2f((unsigned short)(vsA & 0xffff)), xA1 = b2f((unsigned short)(vsA >> 16));
        float xB0 = b2f((unsigned short)(vsB & 0xffff)), xB1 = b2f((unsigned short)(vsB >> 16));
        float zA0 = xA0 + xr0 + b2f((unsigned short)(veA & 0xffff));
        float zA1 = xA1 + xr1 + b2f((unsigned short)(veA >> 16));
        float zB0 = xB0 + xr0 + b2f((unsigned short)(veB & 0xffff));
        float zB1 = xB1 + xr1 + b2f((unsigned short)(veB >> 16));
        zA0 = (zA0 > 0.f) ? zA0 : 0.2f * zA0;
        zA1 = (zA1 > 0.f) ? zA1 : 0.2f * zA1;
        zB0 = (zB0 > 0.f) ? zB0 : 0.2f * zB0;
        zB1 = (zB1 > 0.f) ? zB1 : 0.2f * zB1;
        float pa = zA0 * a0 + zA1 * a1;
        float pb = zB0 * a0 + zB1 * a1;
#pragma unroll
        for (int off = 32; off; off >>= 1) {
            pa += __shfl_xor(pa, off, 64);
            pb += __shfl_xor(pb, off, 64);
        }
        float nm = fmaxf(m, fmaxf(pa, pb));
        float sc = __expf(m - nm);
        float wa = __expf(pa - nm);
        float wb = __expf(pb - nm);
        den  = den * sc + wa + wb;
        acc0 = acc0 * sc + wa * xA0 + wb * xB0;
        acc1 = acc1 * sc + wa * xA1 + wb * xB1;
        m = nm;
    }
    if (it < items) {   // single tail (edge or self-loop)
        int p = pstart + it;
        int s; const unsigned short* ee;
        if (p == pend) { s = n; ee = mean_ee; }
        else { s = csr_src[p]; ee = attr_ee + (size_t)(csr_attr[p] & 63) * D1; }
        unsigned vs = *(const unsigned*)&xl[(size_t)s * D1 + c];
        unsigned ve = *(const unsigned*)&ee[c];
        float xs0 = b2f((unsigned short)(vs & 0xffff)), xs1 = b2f((unsigned short)(vs >> 16));
        float z0 = xs0 + xr0 + b2f((unsigned short)(ve & 0xffff));
        float z1 = xs1 + xr1 + b2f((unsigned short)(ve >> 16));
        z0 = (z0 > 0.f) ? z0 : 0.2f * z0;
        z1 = (z1 > 0.f) ? z1 : 0.2f * z1;
        float ps = z0 * a0 + z1 * a1;
#pragma unroll
        for (int off = 32; off; off >>= 1) ps += __shfl_xor(ps, off, 64);
        float nm = fmaxf(m, ps);
        float sc = __expf(m - nm);
        float w  = __expf(ps - nm);
        den  = den * sc + w;
        acc0 = acc0 * sc + w * xs0;
        acc1 = acc1 * sc + w * xs1;
        m = nm;
    }
    float inv = 1.f / (den + 1e-16f);
    unsigned short o0 = f2b(acc0 * inv + bias[c]);
    unsigned short o1 = f2b(acc1 * inv + bias[c + 1]);
    *(unsigned*)&out[(size_t)n * D1 + c] = ((unsigned)o1 << 16) | o0;
}

// ---------------- merged 4-bit masked GATv2 (shared score, per-bit states) ----------------
__global__ __launch_bounds__(256) void k_gat_m4(const unsigned short* __restrict__ xl,
                                                const unsigned short* __restrict__ xr,
                                                const unsigned short* __restrict__ attr_ee,
                                                const unsigned short* __restrict__ mee,  // 4 rows
                                                const float* __restrict__ att,
                                                const float* __restrict__ bias,
                                                const int* __restrict__ row_ptr,
                                                const int* __restrict__ csr_src,
                                                const int* __restrict__ csr_attr,
                                                const unsigned* __restrict__ mask, int bitbase,
                                                unsigned short* __restrict__ o0,
                                                unsigned short* __restrict__ o1,
                                                unsigned short* __restrict__ o2,
                                                unsigned short* __restrict__ o3) {
    int n = blockIdx.x;
    unsigned mb_n = (mask[n] >> bitbase) & 0xFu;
    if (!mb_n) return;
    __shared__ int lst[256];
    __shared__ int lcnt;
    int t = threadIdx.x, lane = t & 63;
    int c = 2 * t;
    unsigned vr_ = *(const unsigned*)&xr[(size_t)n * D1 + c];
    float xr0 = b2f((unsigned short)(vr_ & 0xffff));
    float xr1 = b2f((unsigned short)(vr_ >> 16));
    float a0 = att[c], a1 = att[c + 1];
    float m[4], den[4], ac0[4], ac1[4];
#pragma unroll
    for (int b = 0; b < 4; ++b) { m[b] = -FLT_MAX; den[b] = 0.f; ac0[b] = 0.f; ac1[b] = 0.f; }
    int pstart = row_ptr[n], pend = row_ptr[n + 1];
    for (int p0 = pstart; p0 < pend; p0 += 256) {
        int chunk = min(256, pend - p0);
        __syncthreads();
        if (t == 0) lcnt = 0;
        __syncthreads();
        unsigned bits = 0; int sv = 0, av = 0;
        if (t < chunk) {
            int p = p0 + t;
            sv = csr_src[p];
            av = csr_attr[p] & 63;
            bits = (mask[sv] >> bitbase) & mb_n & 0xFu;
        }
        bool kept = bits != 0;
        unsigned long long bal = __ballot(kept);
        int base = 0;
        if (lane == 0) base = atomicAdd(&lcnt, __popcll(bal));
        base = __shfl(base, 0, 64);
        int pfx = __popcll(bal & ((1ull << lane) - 1));
        if (kept) lst[base + pfx] = sv | (av << 14) | ((int)bits << 20);
        __syncthreads();
        int cnt = lcnt;
        int i = 0;
        for (; i + 1 < cnt; i += 2) {
            int vA = lst[i], vB = lst[i + 1];
            int sA = vA & 0x3FFF, sB = vB & 0x3FFF;
            unsigned bA = ((unsigned)vA >> 20) & 0xF, bB = ((unsigned)vB >> 20) & 0xF;
            const unsigned short* eA = attr_ee + (size_t)((vA >> 14) & 63) * D1;
            const unsigned short* eB = attr_ee + (size_t)((vB >> 14) & 63) * D1;
            unsigned vsA = *(const unsigned*)&xl[(size_t)sA * D1 + c];
            unsigned veA = *(const unsigned*)&eA[c];
            unsigned vsB = *(const unsigned*)&xl[(size_t)sB * D1 + c];
            unsigned veB = *(const unsigned*)&eB[c];
            float xA0 = b2f((unsigned short)(vsA & 0xffff)), xA1 = b2f((unsigned short)(vsA >> 16));
            float xB0 = b2f((unsigned short)(vsB & 0xffff)), xB1 = b2f((unsigned short)(vsB >> 16));
            float zA0 = xA0 + xr0 + b2f((unsigned short)(veA & 0xffff));
            float zA1 = xA1 + xr1 + b2f((unsigned short)(veA >> 16));
            float zB0 = xB0 + xr0 + b2f((unsigned short)(veB & 0xffff));
            float zB1 = xB1 + xr1 + b2f((unsigned short)(veB >> 16));
            zA0 = (zA0 > 0.f) ? zA0 : 0.2f * zA0;
            zA1 = (zA1 > 0.f) ? zA1 : 0.2f * zA1;
            zB0 = (zB0 > 0.f) ? zB0 : 0.2f * zB0;
            zB1 = (zB1 > 0.f) ? zB1 : 0.2f * zB1;
            float pa = zA0 * a0 + zA1 * a1;
            float pb = zB0 * a0 + zB1 * a1;
#pragma unroll
            for (int off = 32; off; off >>= 1) {
                pa += __shfl_xor(pa, off, 64);
                pb += __shfl_xor(pb, off, 64);
            }
#pragma unroll
            for (int b = 0; b < 4; ++b) {
                if (!(((bA | bB) >> b) & 1)) continue;   // wave-uniform branch
                float pae = ((bA >> b) & 1) ? pa : -FLT_MAX;
                float pbe = ((bB >> b) & 1) ? pb : -FLT_MAX;
                float nm = fmaxf(m[b], fmaxf(pae, pbe));
                float sc = __expf(m[b] - nm);
                float wa = __expf(pae - nm);
                float wb = __expf(pbe - nm);
                den[b] = den[b] * sc + wa + wb;
                ac0[b] = ac0[b] * sc + wa * xA0 + wb * xB0;
                ac1[b] = ac1[b] * sc + wa * xA1 + wb * xB1;
                m[b] = nm;
            }
        }
        if (i < cnt) {
            int vA = lst[i];
            int sA = vA & 0x3FFF;
            unsigned bA = ((unsigned)vA >> 20) & 0xF;
            const unsigned short* eA = attr_ee + (size_t)((vA >> 14) & 63) * D1;
            unsigned vsA = *(const unsigned*)&xl[(size_t)sA * D1 + c];
            unsigned veA = *(const unsigned*)&eA[c];
            float xA0 = b2f((unsigned short)(vsA & 0xffff)), xA1 = b2f((unsigned short)(vsA >> 16));
            float zA0 = xA0 + xr0 + b2f((unsigned short)(veA & 0xffff));
            float zA1 = xA1 + xr1 + b2f((unsigned short)(veA >> 16));
            zA0 = (zA0 > 0.f) ? zA0 : 0.2f * zA0;
            zA1 = (zA1 > 0.f) ? zA1 : 0.2f * zA1;
            float pa = zA0 * a0 + zA1 * a1;
#pragma unroll
            for (int off = 32; off; off >>= 1) pa += __shfl_xor(pa, off, 64);
#pragma unroll
            for (int b = 0; b < 4; ++b) {
                if (!((bA >> b) & 1)) continue;
                float nm = fmaxf(m[b], pa);
                float sc = __expf(m[b] - nm);
                float wa = __expf(pa - nm);
                den[b] = den[b] * sc + wa;
                ac0[b] = ac0[b] * sc + wa * xA0;
                ac1[b] = ac1[b] * sc + wa * xA1;
                m[b] = nm;
            }
        }
    }
    // self-loop (xl[n], per-bit mean_ee) + output
    unsigned vsn = *(const unsigned*)&xl[(size_t)n * D1 + c];
    float xn0 = b2f((unsigned short)(vsn & 0xffff)), xn1 = b2f((unsigned short)(vsn >> 16));
    float bi0 = bias[c], bi1 = bias[c + 1];
#pragma unroll
    for (int b = 0; b < 4; ++b) {
        if (!((mb_n >> b) & 1)) continue;
        unsigned ve = *(const unsigned*)&mee[(size_t)b * D1 + c];
        float z0 = xn0 + xr0 + b2f((unsigned short)(ve & 0xffff));
        float z1 = xn1 + xr1 + b2f((unsigned short)(ve >> 16));
        z0 = (z0 > 0.f) ? z0 : 0.2f * z0;
        z1 = (z1 > 0.f) ? z1 : 0.2f * z1;
        float ps = z0 * a0 + z1 * a1;
#pragma unroll
        for (int off = 32; off; off >>= 1) ps += __shfl_xor(ps, off, 64);
        float nm = fmaxf(m[b], ps);
        float sc = __expf(m[b] - nm);
        float w  = __expf(ps - nm);
        float dd = den[b] * sc + w;
        float A0 = ac0[b] * sc + w * xn0;
        float A1 = ac1[b] * sc + w * xn1;
        float inv = 1.f / (dd + 1e-16f);
        unsigned short q0 = f2b(A0 * inv + bi0);
        unsigned short q1 = f2b(A1 * inv + bi1);
        unsigned pk = ((unsigned)q1 << 16) | q0;
        unsigned short* ob = (b == 0) ? o0 : (b == 1) ? o1 : (b == 2) ? o2 : o3;
        *(unsigned*)&ob[(size_t)n * D1 + c] = pk;
    }
}

// ---------------- full column softmax-aggr (pair-ILP) ----------------
__global__ __launch_bounds__(512) void k_aggr_partial(const unsigned short* __restrict__ x,
                                                      float* __restrict__ part) {
    int c = threadIdx.x;
    int rows = NN / gridDim.x;
    int r0 = blockIdx.x * rows;
    int r1 = r0 + rows;
    float m = -FLT_MAX, den = 0.f, num = 0.f;
    for (int r = r0; r + 1 < r1; r += 2) {
        float va = b2f(x[(size_t)r * D1 + c]);
        float vb = b2f(x[(size_t)(r + 1) * D1 + c]);
        float nm = fmaxf(m, fmaxf(va, vb));
        float sc = __expf(m - nm);
        float wa = __expf(va - nm);
        float wb = __expf(vb - nm);
        den = den * sc + wa + wb;
        num = num * sc + wa * va + wb * vb;
        m = nm;
    }
    part[(blockIdx.x * 3 + 0) * D1 + c] = m;
    part[(blockIdx.x * 3 + 1) * D1 + c] = den;
    part[(blockIdx.x * 3 + 2) * D1 + c] = num;
}

__global__ __launch_bounds__(512) void k_aggr_combine(const float* __restrict__ part, int nb,
                                                      float* __restrict__ out) {
    int c = threadIdx.x;
    float M = -FLT_MAX;
    for (int b = 0; b < nb; ++b) M = fmaxf(M, part[(b * 3) * D1 + c]);
    float den = 0.f, num = 0.f;
    for (int b = 0; b < nb; ++b) {
        float sc = __expf(part[(b * 3 + 0) * D1 + c] - M);
        den += part[(b * 3 + 1) * D1 + c] * sc;
        num += part[(b * 3 + 2) * D1 + c] * sc;
    }
    out[c] = num / den;
}

// ---------------- merged 4-bit masked softmax-aggr ----------------
__global__ __launch_bounds__(512) void k_aggr_partial4(const unsigned short* __restrict__ h0,
                                                       const unsigned short* __restrict__ h1,
                                                       const unsigned short* __restrict__ h2,
                                                       const unsigned short* __restrict__ h3,
                                                       const unsigned* __restrict__ mask, int bitbase,
                                                       float* __restrict__ part) {
    int c = threadIdx.x;
    int rows = NN / gridDim.x;
    int r0 = blockIdx.x * rows;
    int r1 = r0 + rows;
    float m[4], den[4], num[4];
#pragma unroll
    for (int b = 0; b < 4; ++b) { m[b] = -FLT_MAX; den[b] = 0.f; num[b] = 0.f; }
    for (int r = r0; r < r1; ++r) {
        unsigned bits = (mask[r] >> bitbase) & 0xFu;
        if (!bits) continue;
#pragma unroll
        for (int b = 0; b < 4; ++b) {
            if (!((bits >> b) & 1)) continue;
            const unsigned short* hb = (b == 0) ? h0 : (b == 1) ? h1 : (b == 2) ? h2 : h3;
            float v = b2f(hb[(size_t)r * D1 + c]);
            float nm = fmaxf(m[b], v);
            float sc = __expf(m[b] - nm);
            float w  = __expf(v - nm);
            den[b] = den[b] * sc + w;
            num[b] = num[b] * sc + w * v;
            m[b] = nm;
        }
    }
#pragma unroll
    for (int b = 0; b < 4; ++b) {
        part[(((size_t)b * gridDim.x + blockIdx.x) * 3 + 0) * D1 + c] = m[b];
        part[(((size_t)b * gridDim.x + blockIdx.x) * 3 + 1) * D1 + c] = den[b];
        part[(((size_t)b * gridDim.x + blockIdx.x) * 3 + 2) * D1 + c] = num[b];
    }
}

__global__ __launch_bounds__(512) void k_aggr_combine4(const float* __restrict__ part, int nb,
                                                       float* __restrict__ out) {
    int c = threadIdx.x;
    int b = blockIdx.x;                       // bit index 0..3
    const float* pp = part + (size_t)b * nb * 3 * D1;
    float M = -FLT_MAX;
    for (int k = 0; k < nb; ++k) M = fmaxf(M, pp[(k * 3) * D1 + c]);
    float den = 0.f, num = 0.f;
    for (int k = 0; k < nb; ++k) {
        float sc = __expf(pp[(k * 3 + 0) * D1 + c] - M);
        den += pp[(k * 3 + 1) * D1 + c] * sc;
        num += pp[(k * 3 + 2) * D1 + c] * sc;
    }
    out[(size_t)b * D1 + c] = num / den;
}

// ---------------- HGT stage A ----------------
__global__ void k_hgt_a(const float* __restrict__ frame_x, const float* __restrict__ role_x,
                        const float* __restrict__ kqv_f, const float* __restrict__ kqvb_f,
                        const float* __restrict__ kqv_r, const float* __restrict__ kqvb_r,
                        float* __restrict__ kf, float* __restrict__ vf,
                        float* __restrict__ kr, float* __restrict__ qr, float* __restrict__ vr) {
    int b = blockIdx.x, j = threadIdx.x;
    const float *x, *W, *bi;
    float* out;
    if (b == 0)      { x = frame_x;               W = kqv_f;                    bi = kqvb_f;            out = kf; }
    else if (b == 1) { x = frame_x;               W = kqv_f + 2 * D1 * OUTD;    bi = kqvb_f + 2 * OUTD; out = vf; }
    else if (b < 10) { int i = b - 2;  x = role_x + i * D1; W = kqv_r;                 bi = kqvb_r;            out = kr + i * OUTD; }
    else if (b < 18) { int i = b - 10; x = role_x + i * D1; W = kqv_r + D1 * OUTD;     bi = kqvb_r + OUTD;     out = qr + i * OUTD; }
    else             { int i = b - 18; x = role_x + i * D1; W = kqv_r + 2 * D1 * OUTD; bi = kqvb_r + 2 * OUTD; out = vr + i * OUTD; }
    float acc = bi[j];
    for (int k = 0; k < D1; ++k) acc += x[k] * W[k * OUTD + j];
    out[j] = acc;
}

// ---------------- HGT stage B ----------------
__global__ __launch_bounds__(512) void k_hgt_b(const float* __restrict__ kf_g,
                                               const float* __restrict__ vf_g,
                                               const float* __restrict__ kr_g,
                                               const float* __restrict__ qr_g,
                                               const float* __restrict__ vr_g,
                                               const float* __restrict__ a_rel,
                                               const float* __restrict__ m_rel,
                                               const float* __restrict__ p_rel,
                                               const float* __restrict__ aW_f,
                                               const float* __restrict__ ab_f,
                                               const float* __restrict__ aW_r,
                                               const float* __restrict__ ab_r,
                                               float* __restrict__ out_f,
                                               float* __restrict__ out_r) {
    __shared__ float kf[64], vf[64], kr[512], qr[512], vr[512];
    __shared__ float ka1[64], vfm1[64], aggf[64], geluf[64];
    __shared__ float kra2[512], vrm[512], gelur[512];
    __shared__ float al[8][2];
    int t = threadIdx.x;
    if (t < 64) { kf[t] = kf_g[t]; vf[t] = vf_g[t]; }
    kr[t] = kr_g[t]; qr[t] = qr_g[t]; vr[t] = vr_g[t];
    __syncthreads();
    int i = t >> 6, j = t & 63;
    {
        float acc1 = 0.f, acc2 = 0.f;
        for (int k = 0; k < 64; ++k) {
            acc1 += kr[i * 64 + k] * a_rel[2 * 4096 + k * 64 + j];
            acc2 += vr[i * 64 + k] * m_rel[2 * 4096 + k * 64 + j];
        }
        kra2[t] = acc1; vrm[t] = acc2;
    }
    if (t < 64) {
        float acc1 = 0.f, acc2 = 0.f, acc3 = 0.f;
        for (int k = 0; k < 64; ++k) {
            acc1 += kf[k] * a_rel[1 * 4096 + k * 64 + j];
            acc2 += vf[k] * m_rel[0 * 4096 + k * 64 + j];
            acc3 += vf[k] * m_rel[1 * 4096 + k * 64 + j];
        }
        ka1[j] = acc1; aggf[j] = acc2; vfm1[j] = acc3;
    }
    __syncthreads();
    if (t < 8) {
        const float sq = 0.125f;
        float p1 = p_rel[1], p2 = p_rel[2];
        float sfr = 0.f, srr = 0.f;
        for (int d = 0; d < 64; ++d) {
            sfr += qr[t * 64 + d] * ka1[d];
            srr += qr[t * 64 + d] * kra2[t * 64 + d];
        }
        sfr *= sq * p1; srr *= sq * p2;
        float mx = fmaxf(sfr, srr);
        float e0 = __expf(sfr - mx), e1 = __expf(srr - mx);
        float inv = 1.f / (e0 + e1);
        al[t][0] = e0 * inv; al[t][1] = e1 * inv;
    }
    __syncthreads();
    {
        float av = al[i][0] * vfm1[j] + al[i][1] * vrm[t];
        gelur[t] = 0.5f * av * (1.f + erff(av * 0.70710678118654752f));
    }
    if (t < 64) geluf[t] = 0.5f * aggf[t] * (1.f + erff(aggf[t] * 0.70710678118654752f));
    __syncthreads();
    {
        float acc = ab_r[j];
        for (int k = 0; k < 64; ++k) acc += gelur[i * 64 + k] * aW_r[k * 64 + j];
        out_r[t] = acc;
    }
    if (t < 64) {
        float acc = ab_f[j];
        for (int k = 0; k < 64; ++k) acc += geluf[k] * aW_f[k * 64 + j];
        out_f[j] = acc;
    }
}

// ---------------- frame logits + log_softmax ----------------
__global__ void k_frame_logits(const float* __restrict__ out_f, const float* __restrict__ Wfr,
                               const float* __restrict__ bfr, float* __restrict__ flog) {
    __shared__ float xf[64];
    if (threadIdx.x < 64) xf[threadIdx.x] = out_f[threadIdx.x];
    __syncthreads();
    int j = blockIdx.x * blockDim.x + threadIdx.x;
    if (j >= NFR) return;
    float acc = bfr[j];
    for (int k = 0; k < 64; ++k) acc += xf[k] * Wfr[k * NFR + j];
    flog[j] = acc;
}

__global__ __launch_bounds__(512) void k_frame_lsm(const float* __restrict__ flog,
                                                   float* __restrict__ outp) {
    __shared__ float red[512];
    int t = threadIdx.x;
    float m = -FLT_MAX;
    for (int j = t; j < NFR; j += 512) m = fmaxf(m, flog[j]);
    red[t] = m; __syncthreads();
    for (int off = 256; off; off >>= 1) { if (t < off) red[t] = fmaxf(red[t], red[t + off]); __syncthreads(); }
    float M = red[0]; __syncthreads();
    float s = 0.f;
    for (int j = t; j < NFR; j += 512) s += __expf(flog[j] - M);
    red[t] = s; __syncthreads();
    for (int off = 256; off; off >>= 1) { if (t < off) red[t] += red[t + off]; __syncthreads(); }
    float lse = M + logf(red[0]);
    for (int j = t; j < NFR; j += 512) outp[j] = flog[j] - lse;
}

__global__ __launch_bounds__(512) void k_roles(const float* __restrict__ out_r,
                                               const float* __restrict__ Wro,
                                               const float* __restrict__ bro,
                                               float* __restrict__ outp) {
    int t = threadIdx.x;
    int i = t >> 6, j = t & 63;
    __shared__ float xr_s[512];
    xr_s[t] = out_r[t];
    __syncthreads();
    float acc = bro[j];
    for (int k = 0; k < 64; ++k) acc += xr_s[i * 64 + k] * Wro[k * 64 + j];
    float m = acc;
#pragma unroll
    for (int off = 32; off; off >>= 1) m = fmaxf(m, __shfl_xor(m, off, 64));
    float e = __expf(acc - m);
    float s = e;
#pragma unroll
    for (int off = 32; off; off >>= 1) s += __shfl_xor(s, off, 64);
    outp[NFR + t] = acc - m - logf(s);
}

// =====================================================================
extern "C" void kernel_launch(void* const* d_in, const int* in_sizes, int n_in,
                              void* d_out, int out_size, void* d_ws, size_t ws_size,
                              hipStream_t stream) {
    const int* node_pred  = (const int*)d_in[0];
    const int* edge_index = (const int*)d_in[1];
    const int* e_src = edge_index;
    const int* e_dst = edge_index + NE;
    const int* edge_attr  = (const int*)d_in[2];
    const int* arg_nodes  = (const int*)d_in[3];
    const float* pred_emb = (const float*)d_in[4];
    const float* Wl1 = (const float*)d_in[5];
    const float* Wr1 = (const float*)d_in[6];
    const float* We1 = (const float*)d_in[7];
    const float* att1 = (const float*)d_in[8];
    const float* b1  = (const float*)d_in[9];
    const float* Wl2 = (const float*)d_in[10];
    const float* Wr2 = (const float*)d_in[11];
    const float* We2 = (const float*)d_in[12];
    const float* att2 = (const float*)d_in[13];
    const float* b2  = (const float*)d_in[14];
    const float* kqv_f  = (const float*)d_in[15];
    const float* kqvb_f = (const float*)d_in[16];
    const float* kqv_r  = (const float*)d_in[17];
    const float* kqvb_r = (const float*)d_in[18];
    const float* a_rel  = (const float*)d_in[19];
    const float* m_rel  = (const float*)d_in[20];
    const float* p_rel  = (const float*)d_in[21];
    const float* aW_f = (const float*)d_in[22];
    const float* ab_f = (const float*)d_in[23];
    const float* aW_r = (const float*)d_in[24];
    const float* ab_r = (const float*)d_in[25];
    const float* Wfr = (const float*)d_in[26];
    const float* bfr = (const float*)d_in[27];
    const float* Wro = (const float*)d_in[28];
    const float* bro = (const float*)d_in[29];
    float* outp = (float*)d_out;

    // ---- workspace carve ----
    char* base = (char*)d_ws;
    size_t off = 0;
    auto alloc = [&](size_t bytes) -> void* {
        void* p = base + off;
        off += (bytes + 255) & ~(size_t)255;
        return p;
    };
    float* frame_x = (float*)alloc(D1 * 4);
    float* role_x  = (float*)alloc(NA * D1 * 4);
    float* part    = (float*)alloc((size_t)4 * AGG_NB * 3 * D1 * 4);
    float* kf   = (float*)alloc(64 * 4);
    float* vf   = (float*)alloc(64 * 4);
    float* kr   = (float*)alloc(512 * 4);
    float* qr   = (float*)alloc(512 * 4);
    float* vr   = (float*)alloc(512 * 4);
    float* outf = (float*)alloc(64 * 4);
    float* outr = (float*)alloc(512 * 4);
    float* flog = (float*)alloc(NFR * 4);
    int* row_ptr  = (int*)alloc((NN + 1) * 4);
    int* cursor   = (int*)alloc(NN * 4);
    int* csr_src  = (int*)alloc((size_t)NE * 4);
    int* csr_attr = (int*)alloc((size_t)NE * 4);
    unsigned* maskA = (unsigned*)alloc(NN * 4);
    unsigned* maskB = (unsigned*)alloc(NN * 4);
    unsigned* hist  = (unsigned*)alloc(9 * 64 * 4);
    unsigned short* xl    = (unsigned short*)alloc((size_t)NN * D1 * 2);
    unsigned short* xr_   = (unsigned short*)alloc((size_t)NN * D1 * 2);
    unsigned short* hbuf  = (unsigned short*)alloc((size_t)NN * D1 * 2);  // h, then hi(bit0)
    unsigned short* hi1   = (unsigned short*)alloc((size_t)NN * D1 * 2);
    unsigned short* hi2   = (unsigned short*)alloc((size_t)NN * D1 * 2);
    unsigned short* hi3   = (unsigned short*)alloc((size_t)NN * D1 * 2);
    unsigned short* pemb  = (unsigned short*)alloc((size_t)NN * EMBD * 2);
    unsigned short* wl1b  = (unsigned short*)alloc((size_t)EMBD * D1 * 2);
    unsigned short* wr1b  = (unsigned short*)alloc((size_t)EMBD * D1 * 2);
    unsigned short* wl2b  = (unsigned short*)alloc((size_t)D1 * D1 * 2);
    unsigned short* wr2b  = (unsigned short*)alloc((size_t)D1 * D1 * 2);
    unsigned short* attr1 = (unsigned short*)alloc((size_t)NATTR * D1 * 2);
    unsigned short* attr2 = (unsigned short*)alloc((size_t)NATTR * D1 * 2);
    unsigned short* mee1  = (unsigned short*)alloc(D1 * 2);
    unsigned short* mee2  = (unsigned short*)alloc((size_t)NA * D1 * 2);

    // ---- stage 0 ----
    k_cast4<<<(EMBD * D1 / 4 + 255) / 256, 256, 0, stream>>>(Wl1, wl1b, EMBD * D1 / 4);
    k_cast4<<<(EMBD * D1 / 4 + 255) / 256, 256, 0, stream>>>(Wr1, wr1b, EMBD * D1 / 4);
    k_cast4<<<(D1 * D1 / 4 + 255) / 256, 256, 0, stream>>>(Wl2, wl2b, D1 * D1 / 4);
    k_cast4<<<(D1 * D1 / 4 + 255) / 256, 256, 0, stream>>>(Wr2, wr2b, D1 * D1 / 4);
    k_gather_pemb<<<(NN * (EMBD / 4) + 255) / 256, 256, 0, stream>>>(node_pred, pred_emb, pemb);
    k_attr_ee<<<128, 512, 0, stream>>>(pred_emb, We1, We2, attr1, attr2);
    hipMemsetAsync(cursor, 0, sizeof(int) * NN, stream);
    k_indeg<<<256, 256, 0, stream>>>(e_dst, cursor);
    k_scan<<<1, 1024, 0, stream>>>(cursor, row_ptr, cursor);
    k_scatter<<<256, 256, 0, stream>>>(e_src, e_dst, edge_attr, cursor, csr_src, csr_attr);

    // ---- xl1/xr1 GEMMs ----
    dim3 gg(D1 / 64, (NN + 63) / 64);
    k_gemm_bf<<<gg, 256, 0, stream>>>(pemb, wl1b, xl,  NN, EMBD, D1);
    k_gemm_bf<<<gg, 256, 0, stream>>>(pemb, wr1b, xr_, NN, EMBD, D1);

    // ---- k-hop masks ----
    hipMemsetAsync(maskA, 0, sizeof(unsigned) * NN, stream);
    k_mask_seed<<<1, 64, 0, stream>>>(arg_nodes, maskA);
    hipMemsetAsync(maskB, 0, sizeof(unsigned) * NN, stream);
    k_prop<<<256, 256, 0, stream>>>(maskA, maskB, e_src, e_dst);
    hipMemsetAsync(maskA, 0, sizeof(unsigned) * NN, stream);
    k_prop<<<256, 256, 0, stream>>>(maskB, maskA, e_src, e_dst);
    hipMemsetAsync(maskB, 0, sizeof(unsigned) * NN, stream);
    k_prop<<<256, 256, 0, stream>>>(maskA, maskB, e_src, e_dst);

    // ---- histograms + mean edge embeddings ----
    hipMemsetAsync(hist, 0, sizeof(unsigned) * 9 * 64, stream);
    k_hist<<<256, 256, 0, stream>>>(e_src, e_dst, edge_attr, maskB, hist);
    k_mean_ee<<<9, 512, 0, stream>>>(hist, pred_emb, We1, We2, mee1, mee2);

    // ---- GAT layer 1 (full) -> h ----
    k_gat<<<NN, 256, 0, stream>>>(xl, xr_, attr1, mee1, att1, b1,
                                  row_ptr, csr_src, csr_attr, hbuf);
    k_aggr_partial<<<AGG_NB, 512, 0, stream>>>(hbuf, part);
    k_aggr_combine<<<1, 512, 0, stream>>>(part, AGG_NB, frame_x);

    // ---- xl2/xr2 GEMMs (consume h) ----
    k_gemm_bf<<<gg, 256, 0, stream>>>(hbuf, wl2b, xl,  NN, D1, D1);
    k_gemm_bf<<<gg, 256, 0, stream>>>(hbuf, wr2b, xr_, NN, D1, D1);

    // ---- masked GAT-2: two 4-bit merged passes ----
    for (int pb = 0; pb < 2; ++pb) {
        int bb = pb * 4;
        k_gat_m4<<<NN, 256, 0, stream>>>(xl, xr_, attr2, mee2 + (size_t)bb * D1, att2, b2,
                                         row_ptr, csr_src, csr_attr, maskB, bb,
                                         hbuf, hi1, hi2, hi3);
        k_aggr_partial4<<<AGG_NB, 512, 0, stream>>>(hbuf, hi1, hi2, hi3, maskB, bb, part);
        k_aggr_combine4<<<4, 512, 0, stream>>>(part, AGG_NB, role_x + (size_t)bb * D1);
    }

    // ---- HGT + heads ----
    k_hgt_a<<<26, 64, 0, stream>>>(frame_x, role_x, kqv_f, kqvb_f, kqv_r, kqvb_r,
                                   kf, vf, kr, qr, vr);
    k_hgt_b<<<1, 512, 0, stream>>>(kf, vf, kr, qr, vr, a_rel, m_rel, p_rel,
                                   aW_f, ab_f, aW_r, ab_r, outf, outr);
    k_frame_logits<<<(NFR + 255) / 256, 256, 0, stream>>>(outf, Wfr, bfr, flog);
    k_frame_lsm<<<1, 512, 0, stream>>>(flog, outp);
    k_roles<<<1, 512, 0, stream>>>(outr, Wro, bro, outp);
}

// Round 4
// 474.814 us; speedup vs baseline: 2.8080x; 1.6396x over previous
//
#include <hip/hip_runtime.h>
#include <cfloat>
#include <cmath>

static constexpr int NN   = 10000;
static constexpr int NE   = 160000;
static constexpr int NA   = 8;
static constexpr int D1   = 512;
static constexpr int EMBD = 128;
static constexpr int NATTR= 64;
static constexpr int OUTD = 64;
static constexpr int NFR  = 1500;
static constexpr int AGG_NB = 250;   // 250 blocks x 40 rows = 10000

typedef short bf16x8 __attribute__((ext_vector_type(8)));
typedef float f32x4  __attribute__((ext_vector_type(4)));

__device__ __forceinline__ float b2f(unsigned short u) {
    union { unsigned u; float f; } v; v.u = ((unsigned)u) << 16; return v.f;
}
__device__ __forceinline__ unsigned short f2b(float f) {
    union { float f; unsigned u; } v; v.f = f;
    unsigned r = v.u + 0x7FFFu + ((v.u >> 16) & 1u);
    return (unsigned short)(r >> 16);
}

// ---------------- fused cast of the 4 weight matrices fp32 -> bf16 ----------------
__global__ void k_cast_all(const float* __restrict__ W1, const float* __restrict__ W2,
                           const float* __restrict__ W3, const float* __restrict__ W4,
                           unsigned short* __restrict__ o1, unsigned short* __restrict__ o2,
                           unsigned short* __restrict__ o3, unsigned short* __restrict__ o4) {
    int i = blockIdx.x * blockDim.x + threadIdx.x;
    const int n1 = EMBD * D1 / 4;    // 16384
    const int n2 = D1 * D1 / 4;      // 65536
    const float* src; unsigned short* dst; int off;
    if (i < n1)                { src = W1; dst = o1; off = i; }
    else if (i < 2 * n1)       { src = W2; dst = o2; off = i - n1; }
    else if (i < 2 * n1 + n2)  { src = W3; dst = o3; off = i - 2 * n1; }
    else if (i < 2 * n1 + 2 * n2) { src = W4; dst = o4; off = i - 2 * n1 - n2; }
    else return;
    float4 v = ((const float4*)src)[off];
    ushort4 o; o.x = f2b(v.x); o.y = f2b(v.y); o.z = f2b(v.z); o.w = f2b(v.w);
    ((ushort4*)dst)[off] = o;
}

// ---------------- gather p_emb -> bf16 ----------------
__global__ void k_gather_pemb(const int* __restrict__ node_pred,
                              const float* __restrict__ pred_emb,
                              unsigned short* __restrict__ pemb) {
    int idx = blockIdx.x * blockDim.x + threadIdx.x;
    int total = NN * (EMBD / 4);
    if (idx >= total) return;
    int n = idx >> 5, j = idx & 31;
    float4 v = ((const float4*)(pred_emb + (size_t)node_pred[n] * EMBD))[j];
    ushort4 o; o.x = f2b(v.x); o.y = f2b(v.y); o.z = f2b(v.z); o.w = f2b(v.w);
    ((ushort4*)(pemb + (size_t)n * EMBD))[j] = o;
}

// ---------------- attr tables (bf16) ----------------
__global__ void k_attr_ee(const float* __restrict__ pred_emb,
                          const float* __restrict__ We1, const float* __restrict__ We2,
                          unsigned short* __restrict__ t1, unsigned short* __restrict__ t2) {
    int a = blockIdx.x & 63;
    int which = blockIdx.x >> 6;
    const float* We = which ? We2 : We1;
    unsigned short* out = which ? t2 : t1;
    __shared__ float row[EMBD];
    if (threadIdx.x < EMBD) row[threadIdx.x] = pred_emb[a * EMBD + threadIdx.x];
    __syncthreads();
    int c = threadIdx.x;
    float acc = 0.f;
    for (int k = 0; k < EMBD; ++k) acc += row[k] * We[k * D1 + c];
    out[a * D1 + c] = f2b(acc);
}

// ---------------- CSR build ----------------
__global__ void k_indeg(const int* __restrict__ dst, int* __restrict__ counts) {
    int stride = gridDim.x * blockDim.x;
    for (int e = blockIdx.x * blockDim.x + threadIdx.x; e < NE; e += stride)
        atomicAdd(&counts[dst[e]], 1);
}

__global__ __launch_bounds__(1024) void k_scan(const int* __restrict__ counts,
                                               int* __restrict__ row_ptr,
                                               int* __restrict__ cursor) {
    __shared__ int s[1024];
    __shared__ int base_s;
    int t = threadIdx.x;
    if (t == 0) base_s = 0;
    __syncthreads();
    for (int c0 = 0; c0 < NN; c0 += 1024) {
        int v = (c0 + t < NN) ? counts[c0 + t] : 0;
        s[t] = v; __syncthreads();
        for (int off = 1; off < 1024; off <<= 1) {
            int add = (t >= off) ? s[t - off] : 0;
            __syncthreads();
            s[t] += add;
            __syncthreads();
        }
        int base = base_s;
        int excl = base + s[t] - v;
        if (c0 + t < NN) { row_ptr[c0 + t] = excl; cursor[c0 + t] = excl; }
        __syncthreads();
        if (t == 0) base_s = base + s[1023];
        __syncthreads();
    }
    if (t == 0) row_ptr[NN] = base_s;
}

__global__ void k_scatter(const int* __restrict__ src, const int* __restrict__ dst,
                          const int* __restrict__ attr, int* __restrict__ cursor,
                          int* __restrict__ csr_src, int* __restrict__ csr_attr) {
    int stride = gridDim.x * blockDim.x;
    for (int e = blockIdx.x * blockDim.x + threadIdx.x; e < NE; e += stride) {
        int pos = atomicAdd(&cursor[dst[e]], 1);
        csr_src[pos] = src[e];
        csr_attr[pos] = attr[e];
    }
}

// ---------------- k-hop masks ----------------
__global__ void k_mask_seed(const int* __restrict__ arg_nodes, unsigned* __restrict__ mask) {
    if (threadIdx.x < NA) atomicOr(&mask[arg_nodes[threadIdx.x]], 1u << threadIdx.x);
}

__global__ void k_prop(const unsigned* __restrict__ oldm, unsigned* __restrict__ newm,
                       const int* __restrict__ src, const int* __restrict__ dst) {
    int stride = gridDim.x * blockDim.x;
    int t0 = blockIdx.x * blockDim.x + threadIdx.x;
    for (int n = t0; n < NN; n += stride) atomicOr(&newm[n], oldm[n]);
    for (int e = t0; e < NE; e += stride) {
        unsigned v = oldm[dst[e]];
        if (v) atomicOr(&newm[src[e]], v);
    }
}

// ---------------- attr histogram ----------------
__global__ void k_hist(const int* __restrict__ src, const int* __restrict__ dst,
                       const int* __restrict__ attr, const unsigned* __restrict__ mask,
                       unsigned* __restrict__ hist) {
    __shared__ unsigned lh[9 * 64];
    for (int i = threadIdx.x; i < 9 * 64; i += blockDim.x) lh[i] = 0;
    __syncthreads();
    int stride = gridDim.x * blockDim.x;
    for (int e = blockIdx.x * blockDim.x + threadIdx.x; e < NE; e += stride) {
        int a = attr[e] & 63;
        atomicAdd(&lh[a], 1u);
        unsigned bits = mask[src[e]] & mask[dst[e]];
        while (bits) {
            int i = __ffs(bits) - 1;
            bits &= bits - 1;
            atomicAdd(&lh[(1 + i) * 64 + a], 1u);
        }
    }
    __syncthreads();
    for (int i = threadIdx.x; i < 9 * 64; i += blockDim.x)
        if (lh[i]) atomicAdd(&hist[i], lh[i]);
}

// ---------------- mean edge embedding tables (bf16) ----------------
__global__ __launch_bounds__(512) void k_mean_ee(const unsigned* __restrict__ hist,
                                                 const float* __restrict__ pred_emb,
                                                 const float* __restrict__ We1,
                                                 const float* __restrict__ We2,
                                                 unsigned short* __restrict__ mee1,
                                                 unsigned short* __restrict__ mee2) {
    int g = blockIdx.x;
    const float* We = (g == 0) ? We1 : We2;
    unsigned short* out = (g == 0) ? mee1 : (mee2 + (g - 1) * D1);
    __shared__ float cnt[64];
    __shared__ float me[EMBD];
    __shared__ float tot_s;
    if (threadIdx.x < 64) cnt[threadIdx.x] = (float)hist[g * 64 + threadIdx.x];
    __syncthreads();
    if (threadIdx.x == 0) {
        float tt = 0.f;
        for (int a = 0; a < 64; ++a) tt += cnt[a];
        tot_s = fmaxf(tt, 1.0f);
    }
    __syncthreads();
    if (threadIdx.x < EMBD) {
        float acc = 0.f;
        for (int a = 0; a < 64; ++a) acc += cnt[a] * pred_emb[a * EMBD + threadIdx.x];
        me[threadIdx.x] = acc / tot_s;
    }
    __syncthreads();
    int c = threadIdx.x;
    float acc = 0.f;
    for (int k = 0; k < EMBD; ++k) acc += me[k] * We[k * D1 + c];
    out[c] = f2b(acc);
}

// ---------------- bf16 MFMA GEMM (64x64 tile) ----------------
__global__ __launch_bounds__(256) void k_gemm_bf(const unsigned short* __restrict__ A,
                                                 const unsigned short* __restrict__ B,
                                                 unsigned short* __restrict__ C,
                                                 int M, int K, int N) {
    __shared__ unsigned short As[64][40];
    __shared__ unsigned short Bs[64][40];
    int tid = threadIdx.x;
    int wave = tid >> 6, lane = tid & 63;
    int bm = blockIdx.y * 64, bn = blockIdx.x * 64;
    int wr = (wave >> 1) * 32, wc = (wave & 1) * 32;
    f32x4 zero = {0.f, 0.f, 0.f, 0.f};
    f32x4 acc[2][2] = {{zero, zero}, {zero, zero}};
    for (int k0 = 0; k0 < K; k0 += 32) {
#pragma unroll
        for (int i = 0; i < 4; ++i) {
            int idx = tid + 256 * i;
            int row = idx >> 4, kp = (idx & 15) * 2;
            unsigned v = 0;
            if (bm + row < M) v = *(const unsigned*)&A[(size_t)(bm + row) * K + k0 + kp];
            *(unsigned*)&As[row][kp] = v;
        }
#pragma unroll
        for (int i = 0; i < 8; ++i) {
            int idx = tid + 256 * i;
            int k = idx >> 6, n = idx & 63;
            Bs[n][k] = B[(size_t)(k0 + k) * N + bn + n];
        }
        __syncthreads();
        int r = lane & 15, kb = (lane >> 4) * 8;
        bf16x8 a0 = *(const bf16x8*)&As[wr + r][kb];
        bf16x8 a1 = *(const bf16x8*)&As[wr + 16 + r][kb];
        bf16x8 b0 = *(const bf16x8*)&Bs[wc + r][kb];
        bf16x8 b1 = *(const bf16x8*)&Bs[wc + 16 + r][kb];
        acc[0][0] = __builtin_amdgcn_mfma_f32_16x16x32_bf16(a0, b0, acc[0][0], 0, 0, 0);
        acc[0][1] = __builtin_amdgcn_mfma_f32_16x16x32_bf16(a0, b1, acc[0][1], 0, 0, 0);
        acc[1][0] = __builtin_amdgcn_mfma_f32_16x16x32_bf16(a1, b0, acc[1][0], 0, 0, 0);
        acc[1][1] = __builtin_amdgcn_mfma_f32_16x16x32_bf16(a1, b1, acc[1][1], 0, 0, 0);
        __syncthreads();
    }
    int cr = (lane >> 4) * 4, cc = lane & 15;
#pragma unroll
    for (int i = 0; i < 2; ++i)
#pragma unroll
        for (int j = 0; j < 2; ++j)
#pragma unroll
            for (int q = 0; q < 4; ++q) {
                int row = bm + wr + i * 16 + cr + q;
                int col = bn + wc + j * 16 + cc;
                if (row < M) C[(size_t)row * N + col] = f2b(acc[i][j][q]);
            }
}

// ---------------- full-graph GATv2, pair-ILP online softmax ----------------
__global__ __launch_bounds__(256) void k_gat(const unsigned short* __restrict__ xl,
                                             const unsigned short* __restrict__ xr,
                                             const unsigned short* __restrict__ attr_ee,
                                             const unsigned short* __restrict__ mean_ee,
                                             const float* __restrict__ att,
                                             const float* __restrict__ bias,
                                             const int* __restrict__ row_ptr,
                                             const int* __restrict__ csr_src,
                                             const int* __restrict__ csr_attr,
                                             unsigned short* __restrict__ out) {
    int n = blockIdx.x;
    int t = threadIdx.x;
    int c = 2 * t;
    unsigned vr_ = *(const unsigned*)&xr[(size_t)n * D1 + c];
    float xr0 = b2f((unsigned short)(vr_ & 0xffff));
    float xr1 = b2f((unsigned short)(vr_ >> 16));
    float a0 = att[c], a1 = att[c + 1];
    float m = -FLT_MAX, den = 0.f, acc0 = 0.f, acc1 = 0.f;
    int pstart = row_ptr[n], pend = row_ptr[n + 1];
    int items = pend - pstart + 1;     // +1 self-loop
    int it = 0;
    for (; it + 1 < items; it += 2) {
        int pA = pstart + it, pB = pstart + it + 1;
        int sA = csr_src[pA];
        const unsigned short* eA = attr_ee + (size_t)(csr_attr[pA] & 63) * D1;
        int sB; const unsigned short* eB;
        if (pB == pend) { sB = n; eB = mean_ee; }
        else { sB = csr_src[pB]; eB = attr_ee + (size_t)(csr_attr[pB] & 63) * D1; }
        unsigned vsA = *(const unsigned*)&xl[(size_t)sA * D1 + c];
        unsigned veA = *(const unsigned*)&eA[c];
        unsigned vsB = *(const unsigned*)&xl[(size_t)sB * D1 + c];
        unsigned veB = *(const unsigned*)&eB[c];
        float xA0 = b2f((unsigned short)(vsA & 0xffff)), xA1 = b2f((unsigned short)(vsA >> 16));
        float xB0 = b2f((unsigned short)(vsB & 0xffff)), xB1 = b2f((unsigned short)(vsB >> 16));
        float zA0 = xA0 + xr0 + b2f((unsigned short)(veA & 0xffff));
        float zA1 = xA1 + xr1 + b2f((unsigned short)(veA >> 16));
        float zB0 = xB0 + xr0 + b2f((unsigned short)(veB & 0xffff));
        float zB1 = xB1 + xr1 + b2f((unsigned short)(veB >> 16));
        zA0 = (zA0 > 0.f) ? zA0 : 0.2f * zA0;
        zA1 = (zA1 > 0.f) ? zA1 : 0.2f * zA1;
        zB0 = (zB0 > 0.f) ? zB0 : 0.2f * zB0;
        zB1 = (zB1 > 0.f) ? zB1 : 0.2f * zB1;
        float pa = zA0 * a0 + zA1 * a1;
        float pb = zB0 * a0 + zB1 * a1;
#pragma unroll
        for (int off = 32; off; off >>= 1) {
            pa += __shfl_xor(pa, off, 64);
            pb += __shfl_xor(pb, off, 64);
        }
        float nm = fmaxf(m, fmaxf(pa, pb));
        float sc = __expf(m - nm);
        float wa = __expf(pa - nm);
        float wb = __expf(pb - nm);
        den  = den * sc + wa + wb;
        acc0 = acc0 * sc + wa * xA0 + wb * xB0;
        acc1 = acc1 * sc + wa * xA1 + wb * xB1;
        m = nm;
    }
    if (it < items) {
        int p = pstart + it;
        int s; const unsigned short* ee;
        if (p == pend) { s = n; ee = mean_ee; }
        else { s = csr_src[p]; ee = attr_ee + (size_t)(csr_attr[p] & 63) * D1; }
        unsigned vs = *(const unsigned*)&xl[(size_t)s * D1 + c];
        unsigned ve = *(const unsigned*)&ee[c];
        float xs0 = b2f((unsigned short)(vs & 0xffff)), xs1 = b2f((unsigned short)(vs >> 16));
        float z0 = xs0 + xr0 + b2f((unsigned short)(ve & 0xffff));
        float z1 = xs1 + xr1 + b2f((unsigned short)(ve >> 16));
        z0 = (z0 > 0.f) ? z0 : 0.2f * z0;
        z1 = (z1 > 0.f) ? z1 : 0.2f * z1;
        float ps = z0 * a0 + z1 * a1;
#pragma unroll
        for (int off = 32; off; off >>= 1) ps += __shfl_xor(ps, off, 64);
        float nm = fmaxf(m, ps);
        float sc = __expf(m - nm);
        float w  = __expf(ps - nm);
        den  = den * sc + w;
        acc0 = acc0 * sc + w * xs0;
        acc1 = acc1 * sc + w * xs1;
        m = nm;
    }
    float inv = 1.f / (den + 1e-16f);
    unsigned short o0 = f2b(acc0 * inv + bias[c]);
    unsigned short o1 = f2b(acc1 * inv + bias[c + 1]);
    *(unsigned*)&out[(size_t)n * D1 + c] = ((unsigned)o1 << 16) | o0;
}

// ---------------- merged 4-bit masked GATv2 ----------------
__global__ __launch_bounds__(256) void k_gat_m4(const unsigned short* __restrict__ xl,
                                                const unsigned short* __restrict__ xr,
                                                const unsigned short* __restrict__ attr_ee,
                                                const unsigned short* __restrict__ mee,
                                                const float* __restrict__ att,
                                                const float* __restrict__ bias,
                                                const int* __restrict__ row_ptr,
                                                const int* __restrict__ csr_src,
                                                const int* __restrict__ csr_attr,
                                                const unsigned* __restrict__ mask, int bitbase,
                                                unsigned short* __restrict__ o0,
                                                unsigned short* __restrict__ o1,
                                                unsigned short* __restrict__ o2,
                                                unsigned short* __restrict__ o3) {
    int n = blockIdx.x;
    unsigned mb_n = (mask[n] >> bitbase) & 0xFu;
    if (!mb_n) return;
    __shared__ int lst[256];
    __shared__ int lcnt;
    int t = threadIdx.x, lane = t & 63;
    int c = 2 * t;
    unsigned vr_ = *(const unsigned*)&xr[(size_t)n * D1 + c];
    float xr0 = b2f((unsigned short)(vr_ & 0xffff));
    float xr1 = b2f((unsigned short)(vr_ >> 16));
    float a0 = att[c], a1 = att[c + 1];
    float m[4], den[4], ac0[4], ac1[4];
#pragma unroll
    for (int b = 0; b < 4; ++b) { m[b] = -FLT_MAX; den[b] = 0.f; ac0[b] = 0.f; ac1[b] = 0.f; }
    int pstart = row_ptr[n], pend = row_ptr[n + 1];
    for (int p0 = pstart; p0 < pend; p0 += 256) {
        int chunk = min(256, pend - p0);
        __syncthreads();
        if (t == 0) lcnt = 0;
        __syncthreads();
        unsigned bits = 0; int sv = 0, av = 0;
        if (t < chunk) {
            int p = p0 + t;
            sv = csr_src[p];
            av = csr_attr[p] & 63;
            bits = (mask[sv] >> bitbase) & mb_n & 0xFu;
        }
        bool kept = bits != 0;
        unsigned long long bal = __ballot(kept);
        int base = 0;
        if (lane == 0) base = atomicAdd(&lcnt, __popcll(bal));
        base = __shfl(base, 0, 64);
        int pfx = __popcll(bal & ((1ull << lane) - 1));
        if (kept) lst[base + pfx] = sv | (av << 14) | ((int)bits << 20);
        __syncthreads();
        int cnt = lcnt;
        int i = 0;
        for (; i + 1 < cnt; i += 2) {
            int vA = lst[i], vB = lst[i + 1];
            int sA = vA & 0x3FFF, sB = vB & 0x3FFF;
            unsigned bA = ((unsigned)vA >> 20) & 0xF, bB = ((unsigned)vB >> 20) & 0xF;
            const unsigned short* eA = attr_ee + (size_t)((vA >> 14) & 63) * D1;
            const unsigned short* eB = attr_ee + (size_t)((vB >> 14) & 63) * D1;
            unsigned vsA = *(const unsigned*)&xl[(size_t)sA * D1 + c];
            unsigned veA = *(const unsigned*)&eA[c];
            unsigned vsB = *(const unsigned*)&xl[(size_t)sB * D1 + c];
            unsigned veB = *(const unsigned*)&eB[c];
            float xA0 = b2f((unsigned short)(vsA & 0xffff)), xA1 = b2f((unsigned short)(vsA >> 16));
            float xB0 = b2f((unsigned short)(vsB & 0xffff)), xB1 = b2f((unsigned short)(vsB >> 16));
            float zA0 = xA0 + xr0 + b2f((unsigned short)(veA & 0xffff));
            float zA1 = xA1 + xr1 + b2f((unsigned short)(veA >> 16));
            float zB0 = xB0 + xr0 + b2f((unsigned short)(veB & 0xffff));
            float zB1 = xB1 + xr1 + b2f((unsigned short)(veB >> 16));
            zA0 = (zA0 > 0.f) ? zA0 : 0.2f * zA0;
            zA1 = (zA1 > 0.f) ? zA1 : 0.2f * zA1;
            zB0 = (zB0 > 0.f) ? zB0 : 0.2f * zB0;
            zB1 = (zB1 > 0.f) ? zB1 : 0.2f * zB1;
            float pa = zA0 * a0 + zA1 * a1;
            float pb = zB0 * a0 + zB1 * a1;
#pragma unroll
            for (int off = 32; off; off >>= 1) {
                pa += __shfl_xor(pa, off, 64);
                pb += __shfl_xor(pb, off, 64);
            }
#pragma unroll
            for (int b = 0; b < 4; ++b) {
                if (!(((bA | bB) >> b) & 1)) continue;
                float pae = ((bA >> b) & 1) ? pa : -FLT_MAX;
                float pbe = ((bB >> b) & 1) ? pb : -FLT_MAX;
                float nm = fmaxf(m[b], fmaxf(pae, pbe));
                float sc = __expf(m[b] - nm);
                float wa = __expf(pae - nm);
                float wb = __expf(pbe - nm);
                den[b] = den[b] * sc + wa + wb;
                ac0[b] = ac0[b] * sc + wa * xA0 + wb * xB0;
                ac1[b] = ac1[b] * sc + wa * xA1 + wb * xB1;
                m[b] = nm;
            }
        }
        if (i < cnt) {
            int vA = lst[i];
            int sA = vA & 0x3FFF;
            unsigned bA = ((unsigned)vA >> 20) & 0xF;
            const unsigned short* eA = attr_ee + (size_t)((vA >> 14) & 63) * D1;
            unsigned vsA = *(const unsigned*)&xl[(size_t)sA * D1 + c];
            unsigned veA = *(const unsigned*)&eA[c];
            float xA0 = b2f((unsigned short)(vsA & 0xffff)), xA1 = b2f((unsigned short)(vsA >> 16));
            float zA0 = xA0 + xr0 + b2f((unsigned short)(veA & 0xffff));
            float zA1 = xA1 + xr1 + b2f((unsigned short)(veA >> 16));
            zA0 = (zA0 > 0.f) ? zA0 : 0.2f * zA0;
            zA1 = (zA1 > 0.f) ? zA1 : 0.2f * zA1;
            float pa = zA0 * a0 + zA1 * a1;
#pragma unroll
            for (int off = 32; off; off >>= 1) pa += __shfl_xor(pa, off, 64);
#pragma unroll
            for (int b = 0; b < 4; ++b) {
                if (!((bA >> b) & 1)) continue;
                float nm = fmaxf(m[b], pa);
                float sc = __expf(m[b] - nm);
                float wa = __expf(pa - nm);
                den[b] = den[b] * sc + wa;
                ac0[b] = ac0[b] * sc + wa * xA0;
                ac1[b] = ac1[b] * sc + wa * xA1;
                m[b] = nm;
            }
        }
    }
    unsigned vsn = *(const unsigned*)&xl[(size_t)n * D1 + c];
    float xn0 = b2f((unsigned short)(vsn & 0xffff)), xn1 = b2f((unsigned short)(vsn >> 16));
    float bi0 = bias[c], bi1 = bias[c + 1];
#pragma unroll
    for (int b = 0; b < 4; ++b) {
        if (!((mb_n >> b) & 1)) continue;
        unsigned ve = *(const unsigned*)&mee[(size_t)b * D1 + c];
        float z0 = xn0 + xr0 + b2f((unsigned short)(ve & 0xffff));
        float z1 = xn1 + xr1 + b2f((unsigned short)(ve >> 16));
        z0 = (z0 > 0.f) ? z0 : 0.2f * z0;
        z1 = (z1 > 0.f) ? z1 : 0.2f * z1;
        float ps = z0 * a0 + z1 * a1;
#pragma unroll
        for (int off = 32; off; off >>= 1) ps += __shfl_xor(ps, off, 64);
        float nm = fmaxf(m[b], ps);
        float sc = __expf(m[b] - nm);
        float w  = __expf(ps - nm);
        float dd = den[b] * sc + w;
        float A0 = ac0[b] * sc + w * xn0;
        float A1 = ac1[b] * sc + w * xn1;
        float inv = 1.f / (dd + 1e-16f);
        unsigned short q0 = f2b(A0 * inv + bi0);
        unsigned short q1 = f2b(A1 * inv + bi1);
        unsigned pk = ((unsigned)q1 << 16) | q0;
        unsigned short* ob = (b == 0) ? o0 : (b == 1) ? o1 : (b == 2) ? o2 : o3;
        *(unsigned*)&ob[(size_t)n * D1 + c] = pk;
    }
}

// ---------------- full column softmax-aggr partial (pair-ILP) ----------------
__global__ __launch_bounds__(512) void k_aggr_partial(const unsigned short* __restrict__ x,
                                                      float* __restrict__ part) {
    int c = threadIdx.x;
    int rows = NN / gridDim.x;
    int r0 = blockIdx.x * rows;
    int r1 = r0 + rows;
    float m = -FLT_MAX, den = 0.f, num = 0.f;
    for (int r = r0; r + 1 < r1; r += 2) {
        float va = b2f(x[(size_t)r * D1 + c]);
        float vb = b2f(x[(size_t)(r + 1) * D1 + c]);
        float nm = fmaxf(m, fmaxf(va, vb));
        float sc = __expf(m - nm);
        float wa = __expf(va - nm);
        float wb = __expf(vb - nm);
        den = den * sc + wa + wb;
        num = num * sc + wa * va + wb * vb;
        m = nm;
    }
    part[(blockIdx.x * 3 + 0) * D1 + c] = m;
    part[(blockIdx.x * 3 + 1) * D1 + c] = den;
    part[(blockIdx.x * 3 + 2) * D1 + c] = num;
}

// ---------------- merged 4-bit masked softmax-aggr partial ----------------
__global__ __launch_bounds__(512) void k_aggr_partial4(const unsigned short* __restrict__ h0,
                                                       const unsigned short* __restrict__ h1,
                                                       const unsigned short* __restrict__ h2,
                                                       const unsigned short* __restrict__ h3,
                                                       const unsigned* __restrict__ mask, int bitbase,
                                                       float* __restrict__ part) {
    int c = threadIdx.x;
    int rows = NN / gridDim.x;
    int r0 = blockIdx.x * rows;
    int r1 = r0 + rows;
    float m[4], den[4], num[4];
#pragma unroll
    for (int b = 0; b < 4; ++b) { m[b] = -FLT_MAX; den[b] = 0.f; num[b] = 0.f; }
    for (int r = r0; r < r1; ++r) {
        unsigned bits = (mask[r] >> bitbase) & 0xFu;
        if (!bits) continue;
#pragma unroll
        for (int b = 0; b < 4; ++b) {
            if (!((bits >> b) & 1)) continue;
            const unsigned short* hb = (b == 0) ? h0 : (b == 1) ? h1 : (b == 2) ? h2 : h3;
            float v = b2f(hb[(size_t)r * D1 + c]);
            float nm = fmaxf(m[b], v);
            float sc = __expf(m[b] - nm);
            float w  = __expf(v - nm);
            den[b] = den[b] * sc + w;
            num[b] = num[b] * sc + w * v;
            m[b] = nm;
        }
    }
#pragma unroll
    for (int b = 0; b < 4; ++b) {
        part[(((size_t)b * gridDim.x + blockIdx.x) * 3 + 0) * D1 + c] = m[b];
        part[(((size_t)b * gridDim.x + blockIdx.x) * 3 + 1) * D1 + c] = den[b];
        part[(((size_t)b * gridDim.x + blockIdx.x) * 3 + 2) * D1 + c] = num[b];
    }
}

// ---------------- wave-parallel combine: one wave per (set, channel) ----------------
__global__ __launch_bounds__(512) void k_combine_w(const float* __restrict__ part,
                                                   int nb, int nset,
                                                   float* __restrict__ out) {
    int gw = (blockIdx.x * 512 + threadIdx.x) >> 6;   // global wave id
    int lane = threadIdx.x & 63;
    if (gw >= nset * D1) return;
    int s = gw >> 9;           // / 512
    int c = gw & 511;
    const float* pp = part + (size_t)s * nb * 3 * D1;
    float m = -FLT_MAX;
    for (int k = lane; k < nb; k += 64) m = fmaxf(m, pp[(k * 3) * D1 + c]);
#pragma unroll
    for (int off = 32; off; off >>= 1) m = fmaxf(m, __shfl_xor(m, off, 64));
    float den = 0.f, num = 0.f;
    for (int k = lane; k < nb; k += 64) {
        float sc = __expf(pp[(k * 3 + 0) * D1 + c] - m);
        den += pp[(k * 3 + 1) * D1 + c] * sc;
        num += pp[(k * 3 + 2) * D1 + c] * sc;
    }
#pragma unroll
    for (int off = 32; off; off >>= 1) {
        den += __shfl_xor(den, off, 64);
        num += __shfl_xor(num, off, 64);
    }
    if (lane == 0) out[(size_t)s * D1 + c] = num / den;
}

// ---------------- HGT stage A ----------------
__global__ void k_hgt_a(const float* __restrict__ frame_x, const float* __restrict__ role_x,
                        const float* __restrict__ kqv_f, const float* __restrict__ kqvb_f,
                        const float* __restrict__ kqv_r, const float* __restrict__ kqvb_r,
                        float* __restrict__ kf, float* __restrict__ vf,
                        float* __restrict__ kr, float* __restrict__ qr, float* __restrict__ vr) {
    int b = blockIdx.x, j = threadIdx.x;
    const float *x, *W, *bi;
    float* out;
    if (b == 0)      { x = frame_x;               W = kqv_f;                    bi = kqvb_f;            out = kf; }
    else if (b == 1) { x = frame_x;               W = kqv_f + 2 * D1 * OUTD;    bi = kqvb_f + 2 * OUTD; out = vf; }
    else if (b < 10) { int i = b - 2;  x = role_x + i * D1; W = kqv_r;                 bi = kqvb_r;            out = kr + i * OUTD; }
    else if (b < 18) { int i = b - 10; x = role_x + i * D1; W = kqv_r + D1 * OUTD;     bi = kqvb_r + OUTD;     out = qr + i * OUTD; }
    else             { int i = b - 18; x = role_x + i * D1; W = kqv_r + 2 * D1 * OUTD; bi = kqvb_r + 2 * OUTD; out = vr + i * OUTD; }
    float acc = bi[j];
    for (int k = 0; k < D1; ++k) acc += x[k] * W[k * OUTD + j];
    out[j] = acc;
}

// ---------------- fused tail: HGT-B + frame/roles heads + log_softmax ----------------
__global__ __launch_bounds__(512) void k_tail(const float* __restrict__ kf_g,
                                              const float* __restrict__ vf_g,
                                              const float* __restrict__ kr_g,
                                              const float* __restrict__ qr_g,
                                              const float* __restrict__ vr_g,
                                              const float* __restrict__ a_rel,
                                              const float* __restrict__ m_rel,
                                              const float* __restrict__ p_rel,
                                              const float* __restrict__ aW_f,
                                              const float* __restrict__ ab_f,
                                              const float* __restrict__ aW_r,
                                              const float* __restrict__ ab_r,
                                              const float* __restrict__ Wfr,
                                              const float* __restrict__ bfr,
                                              const float* __restrict__ Wro,
                                              const float* __restrict__ bro,
                                              float* __restrict__ outp) {
    __shared__ float kf[64], vf[64], kr[512], qr[512], vr[512];
    __shared__ float ka1[64], vfm1[64], aggf[64], geluf[64];
    __shared__ float kra2[512], vrm[512], gelur[512];
    __shared__ float al[8][2];
    __shared__ float of[64], orr[512];
    __shared__ float flog[NFR];
    __shared__ float red[512];
    int t = threadIdx.x;
    if (t < 64) { kf[t] = kf_g[t]; vf[t] = vf_g[t]; }
    kr[t] = kr_g[t]; qr[t] = qr_g[t]; vr[t] = vr_g[t];
    __syncthreads();
    int i = t >> 6, j = t & 63;
    {
        float acc1 = 0.f, acc2 = 0.f;
        for (int k = 0; k < 64; ++k) {
            acc1 += kr[i * 64 + k] * a_rel[2 * 4096 + k * 64 + j];
            acc2 += vr[i * 64 + k] * m_rel[2 * 4096 + k * 64 + j];
        }
        kra2[t] = acc1; vrm[t] = acc2;
    }
    if (t < 64) {
        float acc1 = 0.f, acc2 = 0.f, acc3 = 0.f;
        for (int k = 0; k < 64; ++k) {
            acc1 += kf[k] * a_rel[1 * 4096 + k * 64 + j];
            acc2 += vf[k] * m_rel[0 * 4096 + k * 64 + j];
            acc3 += vf[k] * m_rel[1 * 4096 + k * 64 + j];
        }
        ka1[j] = acc1; aggf[j] = acc2; vfm1[j] = acc3;
    }
    __syncthreads();
    if (t < 8) {
        const float sq = 0.125f;
        float p1 = p_rel[1], p2 = p_rel[2];
        float sfr = 0.f, srr = 0.f;
        for (int d = 0; d < 64; ++d) {
            sfr += qr[t * 64 + d] * ka1[d];
            srr += qr[t * 64 + d] * kra2[t * 64 + d];
        }
        sfr *= sq * p1; srr *= sq * p2;
        float mx = fmaxf(sfr, srr);
        float e0 = __expf(sfr - mx), e1 = __expf(srr - mx);
        float inv = 1.f / (e0 + e1);
        al[t][0] = e0 * inv; al[t][1] = e1 * inv;
    }
    __syncthreads();
    {
        float av = al[i][0] * vfm1[j] + al[i][1] * vrm[t];
        gelur[t] = 0.5f * av * (1.f + erff(av * 0.70710678118654752f));
    }
    if (t < 64) geluf[t] = 0.5f * aggf[t] * (1.f + erff(aggf[t] * 0.70710678118654752f));
    __syncthreads();
    {
        float acc = ab_r[j];
        for (int k = 0; k < 64; ++k) acc += gelur[i * 64 + k] * aW_r[k * 64 + j];
        orr[t] = acc;
    }
    if (t < 64) {
        float acc = ab_f[j];
        for (int k = 0; k < 64; ++k) acc += geluf[k] * aW_f[k * 64 + j];
        of[j] = acc;
    }
    __syncthreads();
    // ---- frame logits ----
    float lmax = -FLT_MAX;
    for (int q = t; q < NFR; q += 512) {
        float acc = bfr[q];
        for (int k = 0; k < 64; ++k) acc += of[k] * Wfr[k * NFR + q];
        flog[q] = acc;
        lmax = fmaxf(lmax, acc);
    }
    red[t] = lmax; __syncthreads();
    for (int off = 256; off; off >>= 1) { if (t < off) red[t] = fmaxf(red[t], red[t + off]); __syncthreads(); }
    float M = red[0]; __syncthreads();
    float s = 0.f;
    for (int q = t; q < NFR; q += 512) s += __expf(flog[q] - M);
    red[t] = s; __syncthreads();
    for (int off = 256; off; off >>= 1) { if (t < off) red[t] += red[t + off]; __syncthreads(); }
    float lse = M + logf(red[0]);
    for (int q = t; q < NFR; q += 512) outp[q] = flog[q] - lse;
    // ---- roles ----
    {
        float acc = bro[j];
        for (int k = 0; k < 64; ++k) acc += orr[i * 64 + k] * Wro[k * 64 + j];
        float mm = acc;
#pragma unroll
        for (int off = 32; off; off >>= 1) mm = fmaxf(mm, __shfl_xor(mm, off, 64));
        float e = __expf(acc - mm);
        float ss = e;
#pragma unroll
        for (int off = 32; off; off >>= 1) ss += __shfl_xor(ss, off, 64);
        outp[NFR + t] = acc - mm - logf(ss);
    }
}

// =====================================================================
extern "C" void kernel_launch(void* const* d_in, const int* in_sizes, int n_in,
                              void* d_out, int out_size, void* d_ws, size_t ws_size,
                              hipStream_t stream) {
    const int* node_pred  = (const int*)d_in[0];
    const int* edge_index = (const int*)d_in[1];
    const int* e_src = edge_index;
    const int* e_dst = edge_index + NE;
    const int* edge_attr  = (const int*)d_in[2];
    const int* arg_nodes  = (const int*)d_in[3];
    const float* pred_emb = (const float*)d_in[4];
    const float* Wl1 = (const float*)d_in[5];
    const float* Wr1 = (const float*)d_in[6];
    const float* We1 = (const float*)d_in[7];
    const float* att1 = (const float*)d_in[8];
    const float* b1  = (const float*)d_in[9];
    const float* Wl2 = (const float*)d_in[10];
    const float* Wr2 = (const float*)d_in[11];
    const float* We2 = (const float*)d_in[12];
    const float* att2 = (const float*)d_in[13];
    const float* b2  = (const float*)d_in[14];
    const float* kqv_f  = (const float*)d_in[15];
    const float* kqvb_f = (const float*)d_in[16];
    const float* kqv_r  = (const float*)d_in[17];
    const float* kqvb_r = (const float*)d_in[18];
    const float* a_rel  = (const float*)d_in[19];
    const float* m_rel  = (const float*)d_in[20];
    const float* p_rel  = (const float*)d_in[21];
    const float* aW_f = (const float*)d_in[22];
    const float* ab_f = (const float*)d_in[23];
    const float* aW_r = (const float*)d_in[24];
    const float* ab_r = (const float*)d_in[25];
    const float* Wfr = (const float*)d_in[26];
    const float* bfr = (const float*)d_in[27];
    const float* Wro = (const float*)d_in[28];
    const float* bro = (const float*)d_in[29];
    float* outp = (float*)d_out;

    // ---- workspace carve ----
    char* base = (char*)d_ws;
    size_t off = 0;
    auto alloc = [&](size_t bytes) -> void* {
        void* p = base + off;
        off += (bytes + 255) & ~(size_t)255;
        return p;
    };
    float* frame_x = (float*)alloc(D1 * 4);
    float* role_x  = (float*)alloc(NA * D1 * 4);
    float* part    = (float*)alloc((size_t)4 * AGG_NB * 3 * D1 * 4);
    float* kf   = (float*)alloc(64 * 4);
    float* vf   = (float*)alloc(64 * 4);
    float* kr   = (float*)alloc(512 * 4);
    float* qr   = (float*)alloc(512 * 4);
    float* vr   = (float*)alloc(512 * 4);
    int* row_ptr  = (int*)alloc((NN + 1) * 4);
    int* cursor   = (int*)alloc(NN * 4);
    int* csr_src  = (int*)alloc((size_t)NE * 4);
    int* csr_attr = (int*)alloc((size_t)NE * 4);
    unsigned* maskA = (unsigned*)alloc(NN * 4);
    unsigned* maskB = (unsigned*)alloc(NN * 4);
    unsigned* hist  = (unsigned*)alloc(9 * 64 * 4);
    unsigned short* xl    = (unsigned short*)alloc((size_t)NN * D1 * 2);
    unsigned short* xr_   = (unsigned short*)alloc((size_t)NN * D1 * 2);
    unsigned short* hbuf  = (unsigned short*)alloc((size_t)NN * D1 * 2);  // h, then hi(bit0)
    unsigned short* hi1   = (unsigned short*)alloc((size_t)NN * D1 * 2);
    unsigned short* hi2   = (unsigned short*)alloc((size_t)NN * D1 * 2);
    unsigned short* hi3   = (unsigned short*)alloc((size_t)NN * D1 * 2);
    unsigned short* pemb  = (unsigned short*)alloc((size_t)NN * EMBD * 2);
    unsigned short* wl1b  = (unsigned short*)alloc((size_t)EMBD * D1 * 2);
    unsigned short* wr1b  = (unsigned short*)alloc((size_t)EMBD * D1 * 2);
    unsigned short* wl2b  = (unsigned short*)alloc((size_t)D1 * D1 * 2);
    unsigned short* wr2b  = (unsigned short*)alloc((size_t)D1 * D1 * 2);
    unsigned short* attr1 = (unsigned short*)alloc((size_t)NATTR * D1 * 2);
    unsigned short* attr2 = (unsigned short*)alloc((size_t)NATTR * D1 * 2);
    unsigned short* mee1  = (unsigned short*)alloc(D1 * 2);
    unsigned short* mee2  = (unsigned short*)alloc((size_t)NA * D1 * 2);

    // ---- stage 0 ----
    k_cast_all<<<640, 256, 0, stream>>>(Wl1, Wr1, Wl2, Wr2, wl1b, wr1b, wl2b, wr2b);
    k_gather_pemb<<<(NN * (EMBD / 4) + 255) / 256, 256, 0, stream>>>(node_pred, pred_emb, pemb);
    k_attr_ee<<<128, 512, 0, stream>>>(pred_emb, We1, We2, attr1, attr2);
    hipMemsetAsync(cursor, 0, sizeof(int) * NN, stream);
    k_indeg<<<256, 256, 0, stream>>>(e_dst, cursor);
    k_scan<<<1, 1024, 0, stream>>>(cursor, row_ptr, cursor);
    k_scatter<<<256, 256, 0, stream>>>(e_src, e_dst, edge_attr, cursor, csr_src, csr_attr);

    // ---- xl1/xr1 GEMMs ----
    dim3 gg(D1 / 64, (NN + 63) / 64);
    k_gemm_bf<<<gg, 256, 0, stream>>>(pemb, wl1b, xl,  NN, EMBD, D1);
    k_gemm_bf<<<gg, 256, 0, stream>>>(pemb, wr1b, xr_, NN, EMBD, D1);

    // ---- k-hop masks ----
    hipMemsetAsync(maskA, 0, sizeof(unsigned) * NN, stream);
    k_mask_seed<<<1, 64, 0, stream>>>(arg_nodes, maskA);
    hipMemsetAsync(maskB, 0, sizeof(unsigned) * NN, stream);
    k_prop<<<256, 256, 0, stream>>>(maskA, maskB, e_src, e_dst);
    hipMemsetAsync(maskA, 0, sizeof(unsigned) * NN, stream);
    k_prop<<<256, 256, 0, stream>>>(maskB, maskA, e_src, e_dst);
    hipMemsetAsync(maskB, 0, sizeof(unsigned) * NN, stream);
    k_prop<<<256, 256, 0, stream>>>(maskA, maskB, e_src, e_dst);

    // ---- histograms + mean edge embeddings ----
    hipMemsetAsync(hist, 0, sizeof(unsigned) * 9 * 64, stream);
    k_hist<<<256, 256, 0, stream>>>(e_src, e_dst, edge_attr, maskB, hist);
    k_mean_ee<<<9, 512, 0, stream>>>(hist, pred_emb, We1, We2, mee1, mee2);

    // ---- GAT layer 1 (full) -> h ----
    k_gat<<<NN, 256, 0, stream>>>(xl, xr_, attr1, mee1, att1, b1,
                                  row_ptr, csr_src, csr_attr, hbuf);
    k_aggr_partial<<<AGG_NB, 512, 0, stream>>>(hbuf, part);
    k_combine_w<<<64, 512, 0, stream>>>(part, AGG_NB, 1, frame_x);

    // ---- xl2/xr2 GEMMs (consume h) ----
    k_gemm_bf<<<gg, 256, 0, stream>>>(hbuf, wl2b, xl,  NN, D1, D1);
    k_gemm_bf<<<gg, 256, 0, stream>>>(hbuf, wr2b, xr_, NN, D1, D1);

    // ---- masked GAT-2: two 4-bit merged passes ----
    for (int pb = 0; pb < 2; ++pb) {
        int bb = pb * 4;
        k_gat_m4<<<NN, 256, 0, stream>>>(xl, xr_, attr2, mee2 + (size_t)bb * D1, att2, b2,
                                         row_ptr, csr_src, csr_attr, maskB, bb,
                                         hbuf, hi1, hi2, hi3);
        k_aggr_partial4<<<AGG_NB, 512, 0, stream>>>(hbuf, hi1, hi2, hi3, maskB, bb, part);
        k_combine_w<<<256, 512, 0, stream>>>(part, AGG_NB, 4, role_x + (size_t)bb * D1);
    }

    // ---- HGT + fused tail ----
    k_hgt_a<<<26, 64, 0, stream>>>(frame_x, role_x, kqv_f, kqvb_f, kqv_r, kqvb_r,
                                   kf, vf, kr, qr, vr);
    k_tail<<<1, 512, 0, stream>>>(kf, vf, kr, qr, vr, a_rel, m_rel, p_rel,
                                  aW_f, ab_f, aW_r, ab_r, Wfr, bfr, Wro, bro, outp);
}

// Round 5
// 420.650 us; speedup vs baseline: 3.1696x; 1.1288x over previous
//
#include <hip/hip_runtime.h>
#include <cfloat>
#include <cmath>

static constexpr int NN   = 10000;
static constexpr int NE   = 160000;
static constexpr int NA   = 8;
static constexpr int D1   = 512;
static constexpr int EMBD = 128;
static constexpr int NATTR= 64;
static constexpr int OUTD = 64;
static constexpr int NFR  = 1500;
static constexpr int AGG_NB = 250;   // 250 blocks x 40 rows

typedef short bf16x8 __attribute__((ext_vector_type(8)));
typedef float f32x4  __attribute__((ext_vector_type(4)));

__device__ __forceinline__ float b2f(unsigned short u) {
    union { unsigned u; float f; } v; v.u = ((unsigned)u) << 16; return v.f;
}
__device__ __forceinline__ unsigned short f2b(float f) {
    union { float f; unsigned u; } v; v.f = f;
    unsigned r = v.u + 0x7FFFu + ((v.u >> 16) & 1u);
    return (unsigned short)(r >> 16);
}

// ---------------- fused cast of the 4 weight matrices fp32 -> bf16 ----------------
__global__ void k_cast_all(const float* __restrict__ W1, const float* __restrict__ W2,
                           const float* __restrict__ W3, const float* __restrict__ W4,
                           unsigned short* __restrict__ o1, unsigned short* __restrict__ o2,
                           unsigned short* __restrict__ o3, unsigned short* __restrict__ o4) {
    int i = blockIdx.x * blockDim.x + threadIdx.x;
    const int n1 = EMBD * D1 / 4;
    const int n2 = D1 * D1 / 4;
    const float* src; unsigned short* dst; int off;
    if (i < n1)                { src = W1; dst = o1; off = i; }
    else if (i < 2 * n1)       { src = W2; dst = o2; off = i - n1; }
    else if (i < 2 * n1 + n2)  { src = W3; dst = o3; off = i - 2 * n1; }
    else if (i < 2 * n1 + 2 * n2) { src = W4; dst = o4; off = i - 2 * n1 - n2; }
    else return;
    float4 v = ((const float4*)src)[off];
    ushort4 o; o.x = f2b(v.x); o.y = f2b(v.y); o.z = f2b(v.z); o.w = f2b(v.w);
    ((ushort4*)dst)[off] = o;
}

// ---------------- gather p_emb -> bf16 ----------------
__global__ void k_gather_pemb(const int* __restrict__ node_pred,
                              const float* __restrict__ pred_emb,
                              unsigned short* __restrict__ pemb) {
    int idx = blockIdx.x * blockDim.x + threadIdx.x;
    int total = NN * (EMBD / 4);
    if (idx >= total) return;
    int n = idx >> 5, j = idx & 31;
    float4 v = ((const float4*)(pred_emb + (size_t)node_pred[n] * EMBD))[j];
    ushort4 o; o.x = f2b(v.x); o.y = f2b(v.y); o.z = f2b(v.z); o.w = f2b(v.w);
    ((ushort4*)(pemb + (size_t)n * EMBD))[j] = o;
}

// ---------------- attr tables (bf16) ----------------
__global__ void k_attr_ee(const float* __restrict__ pred_emb,
                          const float* __restrict__ We1, const float* __restrict__ We2,
                          unsigned short* __restrict__ t1, unsigned short* __restrict__ t2) {
    int a = blockIdx.x & 63;
    int which = blockIdx.x >> 6;
    const float* We = which ? We2 : We1;
    unsigned short* out = which ? t2 : t1;
    __shared__ float row[EMBD];
    if (threadIdx.x < EMBD) row[threadIdx.x] = pred_emb[a * EMBD + threadIdx.x];
    __syncthreads();
    int c = threadIdx.x;
    float acc = 0.f;
    for (int k = 0; k < EMBD; ++k) acc += row[k] * We[k * D1 + c];
    out[a * D1 + c] = f2b(acc);
}

// ---------------- CSR build ----------------
__global__ void k_indeg(const int* __restrict__ dst, int* __restrict__ counts) {
    int stride = gridDim.x * blockDim.x;
    for (int e = blockIdx.x * blockDim.x + threadIdx.x; e < NE; e += stride)
        atomicAdd(&counts[dst[e]], 1);
}

__global__ __launch_bounds__(1024) void k_scan(const int* __restrict__ counts,
                                               int* __restrict__ row_ptr,
                                               int* __restrict__ cursor) {
    __shared__ int s[1024];
    __shared__ int base_s;
    int t = threadIdx.x;
    if (t == 0) base_s = 0;
    __syncthreads();
    for (int c0 = 0; c0 < NN; c0 += 1024) {
        int v = (c0 + t < NN) ? counts[c0 + t] : 0;
        s[t] = v; __syncthreads();
        for (int off = 1; off < 1024; off <<= 1) {
            int add = (t >= off) ? s[t - off] : 0;
            __syncthreads();
            s[t] += add;
            __syncthreads();
        }
        int base = base_s;
        int excl = base + s[t] - v;
        if (c0 + t < NN) { row_ptr[c0 + t] = excl; cursor[c0 + t] = excl; }
        __syncthreads();
        if (t == 0) base_s = base + s[1023];
        __syncthreads();
    }
    if (t == 0) row_ptr[NN] = base_s;
}

__global__ void k_scatter(const int* __restrict__ src, const int* __restrict__ dst,
                          const int* __restrict__ attr, int* __restrict__ cursor,
                          int* __restrict__ csr_src, int* __restrict__ csr_attr) {
    int stride = gridDim.x * blockDim.x;
    for (int e = blockIdx.x * blockDim.x + threadIdx.x; e < NE; e += stride) {
        int pos = atomicAdd(&cursor[dst[e]], 1);
        csr_src[pos] = src[e];
        csr_attr[pos] = attr[e];
    }
}

// ---------------- k-hop masks ----------------
__global__ void k_mask_seed(const int* __restrict__ arg_nodes, unsigned* __restrict__ mask) {
    if (threadIdx.x < NA) atomicOr(&mask[arg_nodes[threadIdx.x]], 1u << threadIdx.x);
}

__global__ void k_prop(const unsigned* __restrict__ oldm, unsigned* __restrict__ newm,
                       const int* __restrict__ src, const int* __restrict__ dst) {
    int stride = gridDim.x * blockDim.x;
    int t0 = blockIdx.x * blockDim.x + threadIdx.x;
    for (int n = t0; n < NN; n += stride) atomicOr(&newm[n], oldm[n]);
    for (int e = t0; e < NE; e += stride) {
        unsigned v = oldm[dst[e]];
        if (v) atomicOr(&newm[src[e]], v);
    }
}

// ---------------- attr histogram ----------------
__global__ void k_hist(const int* __restrict__ src, const int* __restrict__ dst,
                       const int* __restrict__ attr, const unsigned* __restrict__ mask,
                       unsigned* __restrict__ hist) {
    __shared__ unsigned lh[9 * 64];
    for (int i = threadIdx.x; i < 9 * 64; i += blockDim.x) lh[i] = 0;
    __syncthreads();
    int stride = gridDim.x * blockDim.x;
    for (int e = blockIdx.x * blockDim.x + threadIdx.x; e < NE; e += stride) {
        int a = attr[e] & 63;
        atomicAdd(&lh[a], 1u);
        unsigned bits = mask[src[e]] & mask[dst[e]];
        while (bits) {
            int i = __ffs(bits) - 1;
            bits &= bits - 1;
            atomicAdd(&lh[(1 + i) * 64 + a], 1u);
        }
    }
    __syncthreads();
    for (int i = threadIdx.x; i < 9 * 64; i += blockDim.x)
        if (lh[i]) atomicAdd(&hist[i], lh[i]);
}

// ---------------- mean edge embedding tables (bf16) ----------------
__global__ __launch_bounds__(512) void k_mean_ee(const unsigned* __restrict__ hist,
                                                 const float* __restrict__ pred_emb,
                                                 const float* __restrict__ We1,
                                                 const float* __restrict__ We2,
                                                 unsigned short* __restrict__ mee1,
                                                 unsigned short* __restrict__ mee2) {
    int g = blockIdx.x;
    const float* We = (g == 0) ? We1 : We2;
    unsigned short* out = (g == 0) ? mee1 : (mee2 + (g - 1) * D1);
    __shared__ float cnt[64];
    __shared__ float me[EMBD];
    __shared__ float tot_s;
    if (threadIdx.x < 64) cnt[threadIdx.x] = (float)hist[g * 64 + threadIdx.x];
    __syncthreads();
    if (threadIdx.x == 0) {
        float tt = 0.f;
        for (int a = 0; a < 64; ++a) tt += cnt[a];
        tot_s = fmaxf(tt, 1.0f);
    }
    __syncthreads();
    if (threadIdx.x < EMBD) {
        float acc = 0.f;
        for (int a = 0; a < 64; ++a) acc += cnt[a] * pred_emb[a * EMBD + threadIdx.x];
        me[threadIdx.x] = acc / tot_s;
    }
    __syncthreads();
    int c = threadIdx.x;
    float acc = 0.f;
    for (int k = 0; k < EMBD; ++k) acc += me[k] * We[k * D1 + c];
    out[c] = f2b(acc);
}

// ---------------- dual bf16 MFMA GEMM: z selects (B,C) pair ----------------
__global__ __launch_bounds__(256) void k_gemm_dual(const unsigned short* __restrict__ A,
                                                   const unsigned short* __restrict__ B0,
                                                   const unsigned short* __restrict__ B1,
                                                   unsigned short* __restrict__ C0,
                                                   unsigned short* __restrict__ C1,
                                                   int M, int K, int N) {
    const unsigned short* B = blockIdx.z ? B1 : B0;
    unsigned short* C = blockIdx.z ? C1 : C0;
    __shared__ unsigned short As[64][40];
    __shared__ unsigned short Bs[64][40];
    int tid = threadIdx.x;
    int wave = tid >> 6, lane = tid & 63;
    int bm = blockIdx.y * 64, bn = blockIdx.x * 64;
    int wr = (wave >> 1) * 32, wc = (wave & 1) * 32;
    f32x4 zero = {0.f, 0.f, 0.f, 0.f};
    f32x4 acc[2][2] = {{zero, zero}, {zero, zero}};
    for (int k0 = 0; k0 < K; k0 += 32) {
#pragma unroll
        for (int i = 0; i < 4; ++i) {
            int idx = tid + 256 * i;
            int row = idx >> 4, kp = (idx & 15) * 2;
            unsigned v = 0;
            if (bm + row < M) v = *(const unsigned*)&A[(size_t)(bm + row) * K + k0 + kp];
            *(unsigned*)&As[row][kp] = v;
        }
#pragma unroll
        for (int i = 0; i < 8; ++i) {
            int idx = tid + 256 * i;
            int k = idx >> 6, n = idx & 63;
            Bs[n][k] = B[(size_t)(k0 + k) * N + bn + n];
        }
        __syncthreads();
        int r = lane & 15, kb = (lane >> 4) * 8;
        bf16x8 a0 = *(const bf16x8*)&As[wr + r][kb];
        bf16x8 a1 = *(const bf16x8*)&As[wr + 16 + r][kb];
        bf16x8 b0 = *(const bf16x8*)&Bs[wc + r][kb];
        bf16x8 b1 = *(const bf16x8*)&Bs[wc + 16 + r][kb];
        acc[0][0] = __builtin_amdgcn_mfma_f32_16x16x32_bf16(a0, b0, acc[0][0], 0, 0, 0);
        acc[0][1] = __builtin_amdgcn_mfma_f32_16x16x32_bf16(a0, b1, acc[0][1], 0, 0, 0);
        acc[1][0] = __builtin_amdgcn_mfma_f32_16x16x32_bf16(a1, b0, acc[1][0], 0, 0, 0);
        acc[1][1] = __builtin_amdgcn_mfma_f32_16x16x32_bf16(a1, b1, acc[1][1], 0, 0, 0);
        __syncthreads();
    }
    int cr = (lane >> 4) * 4, cc = lane & 15;
#pragma unroll
    for (int i = 0; i < 2; ++i)
#pragma unroll
        for (int j = 0; j < 2; ++j)
#pragma unroll
            for (int q = 0; q < 4; ++q) {
                int row = bm + wr + i * 16 + cr + q;
                int col = bn + wc + j * 16 + cc;
                if (row < M) C[(size_t)row * N + col] = f2b(acc[i][j][q]);
            }
}

// ---------------- full-graph GATv2, quad-ILP online softmax ----------------
__global__ __launch_bounds__(256) void k_gat(const unsigned short* __restrict__ xl,
                                             const unsigned short* __restrict__ xr,
                                             const unsigned short* __restrict__ attr_ee,
                                             const unsigned short* __restrict__ mean_ee,
                                             const float* __restrict__ att,
                                             const float* __restrict__ bias,
                                             const int* __restrict__ row_ptr,
                                             const int* __restrict__ csr_src,
                                             const int* __restrict__ csr_attr,
                                             unsigned short* __restrict__ out) {
    int n = blockIdx.x;
    int t = threadIdx.x;
    int c = 2 * t;
    unsigned vr_ = *(const unsigned*)&xr[(size_t)n * D1 + c];
    float xr0 = b2f((unsigned short)(vr_ & 0xffff));
    float xr1 = b2f((unsigned short)(vr_ >> 16));
    float a0 = att[c], a1 = att[c + 1];
    float m = -FLT_MAX, den = 0.f, acc0 = 0.f, acc1 = 0.f;
    int pstart = row_ptr[n], pend = row_ptr[n + 1];
    int deg = pend - pstart;
    int items = deg + 1;                       // + self-loop
    for (int it = 0; it < items; it += 4) {
        float xs0[4], xs1[4], ps[4];
#pragma unroll
        for (int u = 0; u < 4; ++u) {
            int item = it + u;
            bool valid = item < items;
            int s; const unsigned short* ee;
            if (!valid || item == deg) { s = n; ee = mean_ee; }
            else {
                int p = pstart + item;
                s = csr_src[p];
                ee = attr_ee + (size_t)(csr_attr[p] & 63) * D1;
            }
            unsigned vs = *(const unsigned*)&xl[(size_t)s * D1 + c];
            unsigned ve = *(const unsigned*)&ee[c];
            float x0 = b2f((unsigned short)(vs & 0xffff));
            float x1 = b2f((unsigned short)(vs >> 16));
            float z0 = x0 + xr0 + b2f((unsigned short)(ve & 0xffff));
            float z1 = x1 + xr1 + b2f((unsigned short)(ve >> 16));
            z0 = (z0 > 0.f) ? z0 : 0.2f * z0;
            z1 = (z1 > 0.f) ? z1 : 0.2f * z1;
            xs0[u] = x0; xs1[u] = x1;
            ps[u] = z0 * a0 + z1 * a1;
        }
#pragma unroll
        for (int off = 32; off; off >>= 1) {
#pragma unroll
            for (int u = 0; u < 4; ++u) ps[u] += __shfl_xor(ps[u], off, 64);
        }
#pragma unroll
        for (int u = 0; u < 4; ++u) if (it + u >= items) ps[u] = -FLT_MAX;
        float nm = fmaxf(fmaxf(fmaxf(ps[0], ps[1]), fmaxf(ps[2], ps[3])), m);
        float sc = __expf(m - nm);
        float w0 = __expf(ps[0] - nm);
        float w1 = __expf(ps[1] - nm);
        float w2 = __expf(ps[2] - nm);
        float w3 = __expf(ps[3] - nm);
        den  = den * sc + ((w0 + w1) + (w2 + w3));
        acc0 = acc0 * sc + ((w0 * xs0[0] + w1 * xs0[1]) + (w2 * xs0[2] + w3 * xs0[3]));
        acc1 = acc1 * sc + ((w0 * xs1[0] + w1 * xs1[1]) + (w2 * xs1[2] + w3 * xs1[3]));
        m = nm;
    }
    float inv = 1.f / (den + 1e-16f);
    unsigned short o0 = f2b(acc0 * inv + bias[c]);
    unsigned short o1 = f2b(acc1 * inv + bias[c + 1]);
    *(unsigned*)&out[(size_t)n * D1 + c] = ((unsigned)o1 << 16) | o0;
}

// ---------------- merged 4-bit masked GATv2 ----------------
__global__ __launch_bounds__(256) void k_gat_m4(const unsigned short* __restrict__ xl,
                                                const unsigned short* __restrict__ xr,
                                                const unsigned short* __restrict__ attr_ee,
                                                const unsigned short* __restrict__ mee,
                                                const float* __restrict__ att,
                                                const float* __restrict__ bias,
                                                const int* __restrict__ row_ptr,
                                                const int* __restrict__ csr_src,
                                                const int* __restrict__ csr_attr,
                                                const unsigned* __restrict__ mask, int bitbase,
                                                unsigned short* __restrict__ o0,
                                                unsigned short* __restrict__ o1,
                                                unsigned short* __restrict__ o2,
                                                unsigned short* __restrict__ o3) {
    int n = blockIdx.x;
    unsigned mb_n = (mask[n] >> bitbase) & 0xFu;
    if (!mb_n) return;
    __shared__ int lst[256];
    __shared__ int lcnt;
    int t = threadIdx.x, lane = t & 63;
    int c = 2 * t;
    unsigned vr_ = *(const unsigned*)&xr[(size_t)n * D1 + c];
    float xr0 = b2f((unsigned short)(vr_ & 0xffff));
    float xr1 = b2f((unsigned short)(vr_ >> 16));
    float a0 = att[c], a1 = att[c + 1];
    float m[4], den[4], ac0[4], ac1[4];
#pragma unroll
    for (int b = 0; b < 4; ++b) { m[b] = -FLT_MAX; den[b] = 0.f; ac0[b] = 0.f; ac1[b] = 0.f; }
    int pstart = row_ptr[n], pend = row_ptr[n + 1];
    for (int p0 = pstart; p0 < pend; p0 += 256) {
        int chunk = min(256, pend - p0);
        __syncthreads();
        if (t == 0) lcnt = 0;
        __syncthreads();
        unsigned bits = 0; int sv = 0, av = 0;
        if (t < chunk) {
            int p = p0 + t;
            sv = csr_src[p];
            av = csr_attr[p] & 63;
            bits = (mask[sv] >> bitbase) & mb_n & 0xFu;
        }
        bool kept = bits != 0;
        unsigned long long bal = __ballot(kept);
        int base = 0;
        if (lane == 0) base = atomicAdd(&lcnt, __popcll(bal));
        base = __shfl(base, 0, 64);
        int pfx = __popcll(bal & ((1ull << lane) - 1));
        if (kept) lst[base + pfx] = sv | (av << 14) | ((int)bits << 20);
        __syncthreads();
        int cnt = lcnt;
        int i = 0;
        for (; i + 1 < cnt; i += 2) {
            int vA = lst[i], vB = lst[i + 1];
            int sA = vA & 0x3FFF, sB = vB & 0x3FFF;
            unsigned bA = ((unsigned)vA >> 20) & 0xF, bB = ((unsigned)vB >> 20) & 0xF;
            const unsigned short* eA = attr_ee + (size_t)((vA >> 14) & 63) * D1;
            const unsigned short* eB = attr_ee + (size_t)((vB >> 14) & 63) * D1;
            unsigned vsA = *(const unsigned*)&xl[(size_t)sA * D1 + c];
            unsigned veA = *(const unsigned*)&eA[c];
            unsigned vsB = *(const unsigned*)&xl[(size_t)sB * D1 + c];
            unsigned veB = *(const unsigned*)&eB[c];
            float xA0 = b2f((unsigned short)(vsA & 0xffff)), xA1 = b2f((unsigned short)(vsA >> 16));
            float xB0 = b2f((unsigned short)(vsB & 0xffff)), xB1 = b2f((unsigned short)(vsB >> 16));
            float zA0 = xA0 + xr0 + b2f((unsigned short)(veA & 0xffff));
            float zA1 = xA1 + xr1 + b2f((unsigned short)(veA >> 16));
            float zB0 = xB0 + xr0 + b2f((unsigned short)(veB & 0xffff));
            float zB1 = xB1 + xr1 + b2f((unsigned short)(veB >> 16));
            zA0 = (zA0 > 0.f) ? zA0 : 0.2f * zA0;
            zA1 = (zA1 > 0.f) ? zA1 : 0.2f * zA1;
            zB0 = (zB0 > 0.f) ? zB0 : 0.2f * zB0;
            zB1 = (zB1 > 0.f) ? zB1 : 0.2f * zB1;
            float pa = zA0 * a0 + zA1 * a1;
            float pb = zB0 * a0 + zB1 * a1;
#pragma unroll
            for (int off = 32; off; off >>= 1) {
                pa += __shfl_xor(pa, off, 64);
                pb += __shfl_xor(pb, off, 64);
            }
#pragma unroll
            for (int b = 0; b < 4; ++b) {
                if (!(((bA | bB) >> b) & 1)) continue;
                float pae = ((bA >> b) & 1) ? pa : -FLT_MAX;
                float pbe = ((bB >> b) & 1) ? pb : -FLT_MAX;
                float nm = fmaxf(m[b], fmaxf(pae, pbe));
                float sc = __expf(m[b] - nm);
                float wa = __expf(pae - nm);
                float wb = __expf(pbe - nm);
                den[b] = den[b] * sc + wa + wb;
                ac0[b] = ac0[b] * sc + wa * xA0 + wb * xB0;
                ac1[b] = ac1[b] * sc + wa * xA1 + wb * xB1;
                m[b] = nm;
            }
        }
        if (i < cnt) {
            int vA = lst[i];
            int sA = vA & 0x3FFF;
            unsigned bA = ((unsigned)vA >> 20) & 0xF;
            const unsigned short* eA = attr_ee + (size_t)((vA >> 14) & 63) * D1;
            unsigned vsA = *(const unsigned*)&xl[(size_t)sA * D1 + c];
            unsigned veA = *(const unsigned*)&eA[c];
            float xA0 = b2f((unsigned short)(vsA & 0xffff)), xA1 = b2f((unsigned short)(vsA >> 16));
            float zA0 = xA0 + xr0 + b2f((unsigned short)(veA & 0xffff));
            float zA1 = xA1 + xr1 + b2f((unsigned short)(veA >> 16));
            zA0 = (zA0 > 0.f) ? zA0 : 0.2f * zA0;
            zA1 = (zA1 > 0.f) ? zA1 : 0.2f * zA1;
            float pa = zA0 * a0 + zA1 * a1;
#pragma unroll
            for (int off = 32; off; off >>= 1) pa += __shfl_xor(pa, off, 64);
#pragma unroll
            for (int b = 0; b < 4; ++b) {
                if (!((bA >> b) & 1)) continue;
                float nm = fmaxf(m[b], pa);
                float sc = __expf(m[b] - nm);
                float wa = __expf(pa - nm);
                den[b] = den[b] * sc + wa;
                ac0[b] = ac0[b] * sc + wa * xA0;
                ac1[b] = ac1[b] * sc + wa * xA1;
                m[b] = nm;
            }
        }
    }
    unsigned vsn = *(const unsigned*)&xl[(size_t)n * D1 + c];
    float xn0 = b2f((unsigned short)(vsn & 0xffff)), xn1 = b2f((unsigned short)(vsn >> 16));
    float bi0 = bias[c], bi1 = bias[c + 1];
#pragma unroll
    for (int b = 0; b < 4; ++b) {
        if (!((mb_n >> b) & 1)) continue;
        unsigned ve = *(const unsigned*)&mee[(size_t)b * D1 + c];
        float z0 = xn0 + xr0 + b2f((unsigned short)(ve & 0xffff));
        float z1 = xn1 + xr1 + b2f((unsigned short)(ve >> 16));
        z0 = (z0 > 0.f) ? z0 : 0.2f * z0;
        z1 = (z1 > 0.f) ? z1 : 0.2f * z1;
        float ps = z0 * a0 + z1 * a1;
#pragma unroll
        for (int off = 32; off; off >>= 1) ps += __shfl_xor(ps, off, 64);
        float nm = fmaxf(m[b], ps);
        float sc = __expf(m[b] - nm);
        float w  = __expf(ps - nm);
        float dd = den[b] * sc + w;
        float A0 = ac0[b] * sc + w * xn0;
        float A1 = ac1[b] * sc + w * xn1;
        float inv = 1.f / (dd + 1e-16f);
        unsigned short q0 = f2b(A0 * inv + bi0);
        unsigned short q1 = f2b(A1 * inv + bi1);
        unsigned pk = ((unsigned)q1 << 16) | q0;
        unsigned short* ob = (b == 0) ? o0 : (b == 1) ? o1 : (b == 2) ? o2 : o3;
        *(unsigned*)&ob[(size_t)n * D1 + c] = pk;
    }
}

// ---------------- full column softmax-aggr partial (quad-ILP) ----------------
__global__ __launch_bounds__(512) void k_aggr_partial(const unsigned short* __restrict__ x,
                                                      float* __restrict__ part) {
    int c = threadIdx.x;
    int rows = NN / gridDim.x;     // 40, divisible by 4
    int r0 = blockIdx.x * rows;
    int r1 = r0 + rows;
    float m = -FLT_MAX, den = 0.f, num = 0.f;
    for (int r = r0; r < r1; r += 4) {
        float v0 = b2f(x[(size_t)r * D1 + c]);
        float v1 = b2f(x[(size_t)(r + 1) * D1 + c]);
        float v2 = b2f(x[(size_t)(r + 2) * D1 + c]);
        float v3 = b2f(x[(size_t)(r + 3) * D1 + c]);
        float nm = fmaxf(fmaxf(fmaxf(v0, v1), fmaxf(v2, v3)), m);
        float sc = __expf(m - nm);
        float w0 = __expf(v0 - nm);
        float w1 = __expf(v1 - nm);
        float w2 = __expf(v2 - nm);
        float w3 = __expf(v3 - nm);
        den = den * sc + ((w0 + w1) + (w2 + w3));
        num = num * sc + ((w0 * v0 + w1 * v1) + (w2 * v2 + w3 * v3));
        m = nm;
    }
    part[(blockIdx.x * 3 + 0) * D1 + c] = m;
    part[(blockIdx.x * 3 + 1) * D1 + c] = den;
    part[(blockIdx.x * 3 + 2) * D1 + c] = num;
}

// ---------------- merged 4-bit masked softmax-aggr partial ----------------
__global__ __launch_bounds__(512) void k_aggr_partial4(const unsigned short* __restrict__ h0,
                                                       const unsigned short* __restrict__ h1,
                                                       const unsigned short* __restrict__ h2,
                                                       const unsigned short* __restrict__ h3,
                                                       const unsigned* __restrict__ mask, int bitbase,
                                                       float* __restrict__ part) {
    int c = threadIdx.x;
    int rows = NN / gridDim.x;
    int r0 = blockIdx.x * rows;
    int r1 = r0 + rows;
    float m[4], den[4], num[4];
#pragma unroll
    for (int b = 0; b < 4; ++b) { m[b] = -FLT_MAX; den[b] = 0.f; num[b] = 0.f; }
    for (int r = r0; r < r1; ++r) {
        unsigned bits = (mask[r] >> bitbase) & 0xFu;
        if (!bits) continue;
#pragma unroll
        for (int b = 0; b < 4; ++b) {
            if (!((bits >> b) & 1)) continue;
            const unsigned short* hb = (b == 0) ? h0 : (b == 1) ? h1 : (b == 2) ? h2 : h3;
            float v = b2f(hb[(size_t)r * D1 + c]);
            float nm = fmaxf(m[b], v);
            float sc = __expf(m[b] - nm);
            float w  = __expf(v - nm);
            den[b] = den[b] * sc + w;
            num[b] = num[b] * sc + w * v;
            m[b] = nm;
        }
    }
#pragma unroll
    for (int b = 0; b < 4; ++b) {
        part[(((size_t)b * gridDim.x + blockIdx.x) * 3 + 0) * D1 + c] = m[b];
        part[(((size_t)b * gridDim.x + blockIdx.x) * 3 + 1) * D1 + c] = den[b];
        part[(((size_t)b * gridDim.x + blockIdx.x) * 3 + 2) * D1 + c] = num[b];
    }
}

// ---------------- wave-parallel combine ----------------
__global__ __launch_bounds__(512) void k_combine_w(const float* __restrict__ part,
                                                   int nb, int nset,
                                                   float* __restrict__ out) {
    int gw = (blockIdx.x * 512 + threadIdx.x) >> 6;
    int lane = threadIdx.x & 63;
    if (gw >= nset * D1) return;
    int s = gw >> 9;
    int c = gw & 511;
    const float* pp = part + (size_t)s * nb * 3 * D1;
    float m = -FLT_MAX;
    for (int k = lane; k < nb; k += 64) m = fmaxf(m, pp[(k * 3) * D1 + c]);
#pragma unroll
    for (int off = 32; off; off >>= 1) m = fmaxf(m, __shfl_xor(m, off, 64));
    float den = 0.f, num = 0.f;
    for (int k = lane; k < nb; k += 64) {
        float sc = __expf(pp[(k * 3 + 0) * D1 + c] - m);
        den += pp[(k * 3 + 1) * D1 + c] * sc;
        num += pp[(k * 3 + 2) * D1 + c] * sc;
    }
#pragma unroll
    for (int off = 32; off; off >>= 1) {
        den += __shfl_xor(den, off, 64);
        num += __shfl_xor(num, off, 64);
    }
    if (lane == 0) out[(size_t)s * D1 + c] = num / den;
}

// ---------------- HGT stage A ----------------
__global__ void k_hgt_a(const float* __restrict__ frame_x, const float* __restrict__ role_x,
                        const float* __restrict__ kqv_f, const float* __restrict__ kqvb_f,
                        const float* __restrict__ kqv_r, const float* __restrict__ kqvb_r,
                        float* __restrict__ kf, float* __restrict__ vf,
                        float* __restrict__ kr, float* __restrict__ qr, float* __restrict__ vr) {
    int b = blockIdx.x, j = threadIdx.x;
    const float *x, *W, *bi;
    float* out;
    if (b == 0)      { x = frame_x;               W = kqv_f;                    bi = kqvb_f;            out = kf; }
    else if (b == 1) { x = frame_x;               W = kqv_f + 2 * D1 * OUTD;    bi = kqvb_f + 2 * OUTD; out = vf; }
    else if (b < 10) { int i = b - 2;  x = role_x + i * D1; W = kqv_r;                 bi = kqvb_r;            out = kr + i * OUTD; }
    else if (b < 18) { int i = b - 10; x = role_x + i * D1; W = kqv_r + D1 * OUTD;     bi = kqvb_r + OUTD;     out = qr + i * OUTD; }
    else             { int i = b - 18; x = role_x + i * D1; W = kqv_r + 2 * D1 * OUTD; bi = kqvb_r + 2 * OUTD; out = vr + i * OUTD; }
    float acc = bi[j];
    for (int k = 0; k < D1; ++k) acc += x[k] * W[k * OUTD + j];
    out[j] = acc;
}

// ---------------- HGT stage B ----------------
__global__ __launch_bounds__(512) void k_hgt_b(const float* __restrict__ kf_g,
                                               const float* __restrict__ vf_g,
                                               const float* __restrict__ kr_g,
                                               const float* __restrict__ qr_g,
                                               const float* __restrict__ vr_g,
                                               const float* __restrict__ a_rel,
                                               const float* __restrict__ m_rel,
                                               const float* __restrict__ p_rel,
                                               const float* __restrict__ aW_f,
                                               const float* __restrict__ ab_f,
                                               const float* __restrict__ aW_r,
                                               const float* __restrict__ ab_r,
                                               float* __restrict__ out_f,
                                               float* __restrict__ out_r) {
    __shared__ float kf[64], vf[64], kr[512], qr[512], vr[512];
    __shared__ float ka1[64], vfm1[64], aggf[64], geluf[64];
    __shared__ float kra2[512], vrm[512], gelur[512];
    __shared__ float al[8][2];
    int t = threadIdx.x;
    if (t < 64) { kf[t] = kf_g[t]; vf[t] = vf_g[t]; }
    kr[t] = kr_g[t]; qr[t] = qr_g[t]; vr[t] = vr_g[t];
    __syncthreads();
    int i = t >> 6, j = t & 63;
    {
        float acc1 = 0.f, acc2 = 0.f;
        for (int k = 0; k < 64; ++k) {
            acc1 += kr[i * 64 + k] * a_rel[2 * 4096 + k * 64 + j];
            acc2 += vr[i * 64 + k] * m_rel[2 * 4096 + k * 64 + j];
        }
        kra2[t] = acc1; vrm[t] = acc2;
    }
    if (t < 64) {
        float acc1 = 0.f, acc2 = 0.f, acc3 = 0.f;
        for (int k = 0; k < 64; ++k) {
            acc1 += kf[k] * a_rel[1 * 4096 + k * 64 + j];
            acc2 += vf[k] * m_rel[0 * 4096 + k * 64 + j];
            acc3 += vf[k] * m_rel[1 * 4096 + k * 64 + j];
        }
        ka1[j] = acc1; aggf[j] = acc2; vfm1[j] = acc3;
    }
    __syncthreads();
    if (t < 8) {
        const float sq = 0.125f;
        float p1 = p_rel[1], p2 = p_rel[2];
        float sfr = 0.f, srr = 0.f;
        for (int d = 0; d < 64; ++d) {
            sfr += qr[t * 64 + d] * ka1[d];
            srr += qr[t * 64 + d] * kra2[t * 64 + d];
        }
        sfr *= sq * p1; srr *= sq * p2;
        float mx = fmaxf(sfr, srr);
        float e0 = __expf(sfr - mx), e1 = __expf(srr - mx);
        float inv = 1.f / (e0 + e1);
        al[t][0] = e0 * inv; al[t][1] = e1 * inv;
    }
    __syncthreads();
    {
        float av = al[i][0] * vfm1[j] + al[i][1] * vrm[t];
        gelur[t] = 0.5f * av * (1.f + erff(av * 0.70710678118654752f));
    }
    if (t < 64) geluf[t] = 0.5f * aggf[t] * (1.f + erff(aggf[t] * 0.70710678118654752f));
    __syncthreads();
    {
        float acc = ab_r[j];
        for (int k = 0; k < 64; ++k) acc += gelur[i * 64 + k] * aW_r[k * 64 + j];
        out_r[t] = acc;
    }
    if (t < 64) {
        float acc = ab_f[j];
        for (int k = 0; k < 64; ++k) acc += geluf[k] * aW_f[k * 64 + j];
        out_f[j] = acc;
    }
}

// ---------------- frame logits (grid-parallel, coalesced Wfr) ----------------
__global__ void k_frame_logits(const float* __restrict__ out_f, const float* __restrict__ Wfr,
                               const float* __restrict__ bfr, float* __restrict__ flog) {
    __shared__ float xf[64];
    if (threadIdx.x < 64) xf[threadIdx.x] = out_f[threadIdx.x];
    __syncthreads();
    int j = blockIdx.x * blockDim.x + threadIdx.x;
    if (j >= NFR) return;
    float acc = bfr[j];
    for (int k = 0; k < 64; ++k) acc += xf[k] * Wfr[k * NFR + j];
    flog[j] = acc;
}

// ---------------- final: frame log_softmax + roles head ----------------
__global__ __launch_bounds__(512) void k_final(const float* __restrict__ flog,
                                               const float* __restrict__ out_r,
                                               const float* __restrict__ Wro,
                                               const float* __restrict__ bro,
                                               float* __restrict__ outp) {
    __shared__ float red[512];
    __shared__ float xr_s[512];
    int t = threadIdx.x;
    int i = t >> 6, j = t & 63;
    xr_s[t] = out_r[t];
    // roles head (wave-local)
    float racc = bro[j];
    for (int k = 0; k < 64; ++k) racc += xr_s[i * 64 + k] * Wro[k * 64 + j];
    float rm = racc;
#pragma unroll
    for (int off = 32; off; off >>= 1) rm = fmaxf(rm, __shfl_xor(rm, off, 64));
    float re = __expf(racc - rm);
    float rs = re;
#pragma unroll
    for (int off = 32; off; off >>= 1) rs += __shfl_xor(rs, off, 64);
    outp[NFR + t] = racc - rm - logf(rs);
    // frame log-softmax
    float m = -FLT_MAX;
    for (int q = t; q < NFR; q += 512) m = fmaxf(m, flog[q]);
    red[t] = m; __syncthreads();
    for (int off = 256; off; off >>= 1) { if (t < off) red[t] = fmaxf(red[t], red[t + off]); __syncthreads(); }
    float M = red[0]; __syncthreads();
    float s = 0.f;
    for (int q = t; q < NFR; q += 512) s += __expf(flog[q] - M);
    red[t] = s; __syncthreads();
    for (int off = 256; off; off >>= 1) { if (t < off) red[t] += red[t + off]; __syncthreads(); }
    float lse = M + logf(red[0]);
    for (int q = t; q < NFR; q += 512) outp[q] = flog[q] - lse;
}

// =====================================================================
extern "C" void kernel_launch(void* const* d_in, const int* in_sizes, int n_in,
                              void* d_out, int out_size, void* d_ws, size_t ws_size,
                              hipStream_t stream) {
    const int* node_pred  = (const int*)d_in[0];
    const int* edge_index = (const int*)d_in[1];
    const int* e_src = edge_index;
    const int* e_dst = edge_index + NE;
    const int* edge_attr  = (const int*)d_in[2];
    const int* arg_nodes  = (const int*)d_in[3];
    const float* pred_emb = (const float*)d_in[4];
    const float* Wl1 = (const float*)d_in[5];
    const float* Wr1 = (const float*)d_in[6];
    const float* We1 = (const float*)d_in[7];
    const float* att1 = (const float*)d_in[8];
    const float* b1  = (const float*)d_in[9];
    const float* Wl2 = (const float*)d_in[10];
    const float* Wr2 = (const float*)d_in[11];
    const float* We2 = (const float*)d_in[12];
    const float* att2 = (const float*)d_in[13];
    const float* b2  = (const float*)d_in[14];
    const float* kqv_f  = (const float*)d_in[15];
    const float* kqvb_f = (const float*)d_in[16];
    const float* kqv_r  = (const float*)d_in[17];
    const float* kqvb_r = (const float*)d_in[18];
    const float* a_rel  = (const float*)d_in[19];
    const float* m_rel  = (const float*)d_in[20];
    const float* p_rel  = (const float*)d_in[21];
    const float* aW_f = (const float*)d_in[22];
    const float* ab_f = (const float*)d_in[23];
    const float* aW_r = (const float*)d_in[24];
    const float* ab_r = (const float*)d_in[25];
    const float* Wfr = (const float*)d_in[26];
    const float* bfr = (const float*)d_in[27];
    const float* Wro = (const float*)d_in[28];
    const float* bro = (const float*)d_in[29];
    float* outp = (float*)d_out;

    // ---- workspace carve ----
    char* base = (char*)d_ws;
    size_t off = 0;
    auto alloc = [&](size_t bytes) -> void* {
        void* p = base + off;
        off += (bytes + 255) & ~(size_t)255;
        return p;
    };
    float* frame_x = (float*)alloc(D1 * 4);
    float* role_x  = (float*)alloc(NA * D1 * 4);
    float* part    = (float*)alloc((size_t)4 * AGG_NB * 3 * D1 * 4);
    float* kf   = (float*)alloc(64 * 4);
    float* vf   = (float*)alloc(64 * 4);
    float* kr   = (float*)alloc(512 * 4);
    float* qr   = (float*)alloc(512 * 4);
    float* vr   = (float*)alloc(512 * 4);
    float* outf = (float*)alloc(64 * 4);
    float* outr = (float*)alloc(512 * 4);
    float* flog = (float*)alloc(NFR * 4);
    int* row_ptr  = (int*)alloc((NN + 1) * 4);
    // ---- zero-region start (single memset covers cursor..hist) ----
    int* cursor   = (int*)alloc(NN * 4);
    unsigned* maskA = (unsigned*)alloc(NN * 4);
    unsigned* maskB = (unsigned*)alloc(NN * 4);
    unsigned* maskC = (unsigned*)alloc(NN * 4);
    unsigned* hist  = (unsigned*)alloc(9 * 64 * 4);
    size_t zero_end = off;
    size_t zero_beg = (char*)cursor - base;
    int* csr_src  = (int*)alloc((size_t)NE * 4);
    int* csr_attr = (int*)alloc((size_t)NE * 4);
    unsigned short* xl    = (unsigned short*)alloc((size_t)NN * D1 * 2);
    unsigned short* xr_   = (unsigned short*)alloc((size_t)NN * D1 * 2);
    unsigned short* hbuf  = (unsigned short*)alloc((size_t)NN * D1 * 2);  // h, then hi(bit0)
    unsigned short* hi1   = (unsigned short*)alloc((size_t)NN * D1 * 2);
    unsigned short* hi2   = (unsigned short*)alloc((size_t)NN * D1 * 2);
    unsigned short* hi3   = (unsigned short*)alloc((size_t)NN * D1 * 2);
    unsigned short* pemb  = (unsigned short*)alloc((size_t)NN * EMBD * 2);
    unsigned short* wl1b  = (unsigned short*)alloc((size_t)EMBD * D1 * 2);
    unsigned short* wr1b  = (unsigned short*)alloc((size_t)EMBD * D1 * 2);
    unsigned short* wl2b  = (unsigned short*)alloc((size_t)D1 * D1 * 2);
    unsigned short* wr2b  = (unsigned short*)alloc((size_t)D1 * D1 * 2);
    unsigned short* attr1 = (unsigned short*)alloc((size_t)NATTR * D1 * 2);
    unsigned short* attr2 = (unsigned short*)alloc((size_t)NATTR * D1 * 2);
    unsigned short* mee1  = (unsigned short*)alloc(D1 * 2);
    unsigned short* mee2  = (unsigned short*)alloc((size_t)NA * D1 * 2);

    // ---- stage 0 ----
    hipMemsetAsync(base + zero_beg, 0, zero_end - zero_beg, stream);
    k_cast_all<<<640, 256, 0, stream>>>(Wl1, Wr1, Wl2, Wr2, wl1b, wr1b, wl2b, wr2b);
    k_gather_pemb<<<(NN * (EMBD / 4) + 255) / 256, 256, 0, stream>>>(node_pred, pred_emb, pemb);
    k_attr_ee<<<128, 512, 0, stream>>>(pred_emb, We1, We2, attr1, attr2);
    k_indeg<<<256, 256, 0, stream>>>(e_dst, cursor);
    k_scan<<<1, 1024, 0, stream>>>(cursor, row_ptr, cursor);
    k_scatter<<<256, 256, 0, stream>>>(e_src, e_dst, edge_attr, cursor, csr_src, csr_attr);

    // ---- xl1/xr1 GEMMs (dual) ----
    dim3 gg(D1 / 64, (NN + 63) / 64, 2);
    k_gemm_dual<<<gg, 256, 0, stream>>>(pemb, wl1b, wr1b, xl, xr_, NN, EMBD, D1);

    // ---- k-hop masks: A -> B -> C -> A (targets pre-zeroed; A holds seeds, subset-safe) ----
    k_mask_seed<<<1, 64, 0, stream>>>(arg_nodes, maskA);
    k_prop<<<256, 256, 0, stream>>>(maskA, maskB, e_src, e_dst);
    k_prop<<<256, 256, 0, stream>>>(maskB, maskC, e_src, e_dst);
    k_prop<<<256, 256, 0, stream>>>(maskC, maskA, e_src, e_dst);

    // ---- histograms + mean edge embeddings ----
    k_hist<<<256, 256, 0, stream>>>(e_src, e_dst, edge_attr, maskA, hist);
    k_mean_ee<<<9, 512, 0, stream>>>(hist, pred_emb, We1, We2, mee1, mee2);

    // ---- GAT layer 1 (full) -> h ----
    k_gat<<<NN, 256, 0, stream>>>(xl, xr_, attr1, mee1, att1, b1,
                                  row_ptr, csr_src, csr_attr, hbuf);
    k_aggr_partial<<<AGG_NB, 512, 0, stream>>>(hbuf, part);
    k_combine_w<<<64, 512, 0, stream>>>(part, AGG_NB, 1, frame_x);

    // ---- xl2/xr2 GEMMs (dual, consume h) ----
    k_gemm_dual<<<gg, 256, 0, stream>>>(hbuf, wl2b, wr2b, xl, xr_, NN, D1, D1);

    // ---- masked GAT-2: two 4-bit merged passes ----
    for (int pb = 0; pb < 2; ++pb) {
        int bb = pb * 4;
        k_gat_m4<<<NN, 256, 0, stream>>>(xl, xr_, attr2, mee2 + (size_t)bb * D1, att2, b2,
                                         row_ptr, csr_src, csr_attr, maskA, bb,
                                         hbuf, hi1, hi2, hi3);
        k_aggr_partial4<<<AGG_NB, 512, 0, stream>>>(hbuf, hi1, hi2, hi3, maskA, bb, part);
        k_combine_w<<<256, 512, 0, stream>>>(part, AGG_NB, 4, role_x + (size_t)bb * D1);
    }

    // ---- HGT + heads ----
    k_hgt_a<<<26, 64, 0, stream>>>(frame_x, role_x, kqv_f, kqvb_f, kqv_r, kqvb_r,
                                   kf, vf, kr, qr, vr);
    k_hgt_b<<<1, 512, 0, stream>>>(kf, vf, kr, qr, vr, a_rel, m_rel, p_rel,
                                   aW_f, ab_f, aW_r, ab_r, outf, outr);
    k_frame_logits<<<(NFR + 255) / 256, 256, 0, stream>>>(outf, Wfr, bfr, flog);
    k_final<<<1, 512, 0, stream>>>(flog, outr, Wro, bro, outp);
}